// Round 3
// baseline (642.274 us; speedup 1.0000x reference)
//
#include <hip/hip_runtime.h>
#include <hip/hip_bf16.h>

// GAT, 3 layers: (H=8,C=8,concat) -> relu -> (8,8,concat) -> relu -> (4,1,mean)
// N=50000 nodes, E=800000 edges + N self-loops.
//   0. Detect edge_index word stride (int32 vs int64) on device.
//   1. Build dst-CSR once (zero -> degree count -> 1-block scan -> scatter).
//   2. Per layer: fused GEMM+attention-score kernel, then per-node gather with
//      two-pass stable softmax (emax = leaky(a_i + max a_j); leaky monotone,
//      a_i constant per segment).
// All graph-derived indices are clamped identically at produce/consume sites:
// a bad index gives a wrong (diagnosable) result, never a memory fault.
// No hipMemset/hipMemcpy inside launch; everything is kernels on `stream`.

#define FDIM 64

__global__ __launch_bounds__(256) void zero_int_kernel(int* __restrict__ p, int n) {
  int i = blockIdx.x * 256 + threadIdx.x;
  if (i < n) p[i] = 0;
}

// int64 upload => odd 32-bit words are high words of ids < 2^31 => all zero.
// int32 upload => odd words are random node ids => some nonzero. flag = word stride.
__global__ __launch_bounds__(256) void detect_stride_kernel(
    const int* __restrict__ ei, int E, int* __restrict__ flag) {
  __shared__ int any;
  if (threadIdx.x == 0) any = 0;
  __syncthreads();
  int idx = 2 * threadIdx.x + 1;
  int v = (idx < 2 * E) ? ei[idx] : 0;
  if (v != 0) atomicOr(&any, 1);
  __syncthreads();
  if (threadIdx.x == 0) *flag = any ? 1 : 2;
}

__device__ __forceinline__ int clampN(int v, int N) {
  return ((unsigned)v >= (unsigned)N) ? 0 : v;
}

__global__ __launch_bounds__(256) void count_deg_kernel(
    const int* __restrict__ ei, const int* __restrict__ flag, int E, int N,
    int* __restrict__ deg) {
  int st = *flag;
  int e = blockIdx.x * 256 + threadIdx.x;
  int ET = E + N;
  if (e >= ET) return;
  int dst = (e < E) ? clampN(ei[(size_t)st * (E + e)], N) : (e - E);
  atomicAdd(&deg[dst], 1);
}

__global__ __launch_bounds__(1024) void scan_kernel(
    const int* __restrict__ deg, int* __restrict__ rowstart,
    int* __restrict__ fill, int N, int total) {
  __shared__ int part[1024];
  int t = threadIdx.x;
  int chunk = (N + 1023) >> 10;
  int lo = t * chunk;
  int hi = lo + chunk; if (hi > N) hi = N;
  int s = 0;
  for (int i = lo; i < hi; ++i) s += deg[i];
  part[t] = s;
  __syncthreads();
  for (int off = 1; off < 1024; off <<= 1) {   // Hillis-Steele inclusive
    int v = (t >= off) ? part[t - off] : 0;
    __syncthreads();
    part[t] += v;
    __syncthreads();
  }
  int run = part[t] - s;  // exclusive base
  for (int i = lo; i < hi; ++i) {
    rowstart[i] = run;
    fill[i] = run;
    run += deg[i];
  }
  if (t == 0) rowstart[N] = total;
}

__global__ __launch_bounds__(256) void scatter_kernel(
    const int* __restrict__ ei, const int* __restrict__ flag, int E, int N,
    int* __restrict__ fill, int* __restrict__ col) {
  int st = *flag;
  int e = blockIdx.x * 256 + threadIdx.x;
  int ET = E + N;
  if (e >= ET) return;
  int src, dst;
  if (e < E) {
    src = clampN(ei[(size_t)st * e], N);
    dst = clampN(ei[(size_t)st * (E + e)], N);
  } else {
    src = e - E; dst = e - E;
  }
  int pos = atomicAdd(&fill[dst], 1);
  if ((unsigned)pos < (unsigned)ET) col[pos] = src;
}

// Layers 1-2: xw = x@W (64x64) + per-node attention scores.
// Block = 256 threads = 4 nodes x 64 lanes (lane = h*8+c).
__global__ __launch_bounds__(256) void gemm_att64_kernel(
    const float* __restrict__ x, const float* __restrict__ W,
    const float* __restrict__ att, int N, float* __restrict__ xw,
    float* __restrict__ ai, float* __restrict__ aj) {
  __shared__ float Wl[64 * 64];
  int tid = threadIdx.x;
  for (int i = tid; i < 64 * 64; i += 256) Wl[i] = W[i];
  __syncthreads();
  int n = blockIdx.x * 4 + (tid >> 6);
  if (n >= N) return;
  int j = tid & 63;
  const float* xr = x + (size_t)n * 64;
  float acc = 0.f;
  #pragma unroll
  for (int k = 0; k < 64; ++k) acc += xr[k] * Wl[k * 64 + j];
  xw[(size_t)n * 64 + j] = acc;
  int h = j >> 3, c = j & 7;
  float pi = acc * att[h * 16 + c];       // att[0,h,:C] -> a_i (target side)
  float pj = acc * att[h * 16 + 8 + c];   // att[0,h,C:] -> a_j (source side)
  #pragma unroll
  for (int off = 1; off < 8; off <<= 1) {
    pi += __shfl_xor(pi, off, 8);
    pj += __shfl_xor(pj, off, 8);
  }
  if (c == 0) {
    ai[n * 8 + h] = pi;
    aj[n * 8 + h] = pj;
  }
}

// Layer 3: xw = x@W3 (64x4), H=4, C=1. One lane per (node, head).
__global__ __launch_bounds__(256) void gemm_att4_kernel(
    const float* __restrict__ x, const float* __restrict__ W,
    const float* __restrict__ att, int N, float* __restrict__ xw,
    float* __restrict__ ai, float* __restrict__ aj) {
  int t = blockIdx.x * 256 + threadIdx.x;
  int n = t >> 2;
  if (n >= N) return;
  int j = t & 3;
  const float* xr = x + (size_t)n * 64;
  float acc = 0.f;
  #pragma unroll
  for (int k = 0; k < 64; ++k) acc += xr[k] * W[k * 4 + j];
  xw[n * 4 + j] = acc;
  ai[n * 4 + j] = acc * att[j * 2];
  aj[n * 4 + j] = acc * att[j * 2 + 1];
}

// Layers 1-2 aggregation: block = 4 nodes x 64 lanes (lane = f = h*8+c).
__global__ __launch_bounds__(256) void gather64_kernel(
    const float* __restrict__ xw, const float* __restrict__ ai,
    const float* __restrict__ aj, const int* __restrict__ rowstart,
    const int* __restrict__ col, const float* __restrict__ bias, int N,
    int relu, float* __restrict__ out) {
  int n = blockIdx.x * 4 + (threadIdx.x >> 6);
  if (n >= N) return;
  int f = threadIdx.x & 63;
  int h = f >> 3;
  int r0 = rowstart[n], r1 = rowstart[n + 1];
  float ain = ai[n * 8 + h];
  float smax = -1e30f;
  for (int e = r0; e < r1; ++e) {
    int s = clampN(col[e], N);
    smax = fmaxf(smax, aj[s * 8 + h]);
  }
  float m = ain + smax;
  m = (m > 0.f) ? m : 0.2f * m;  // emax = leaky(a_i + max a_j)
  float denom = 0.f, acc = 0.f;
  for (int e = r0; e < r1; ++e) {
    int s = clampN(col[e], N);
    float ev = ain + aj[s * 8 + h];
    ev = (ev > 0.f) ? ev : 0.2f * ev;
    float p = __expf(ev - m);
    denom += p;                           // redundant across lanes sharing h
    acc += p * xw[(size_t)s * 64 + f];    // coalesced 256B row read
  }
  float o = acc / denom + bias[f];
  if (relu) o = fmaxf(o, 0.f);
  out[(size_t)n * 64 + f] = o;
}

// Layer 3 aggregation + head-mean + bias. 4 lanes per node.
__global__ __launch_bounds__(256) void gather4_kernel(
    const float* __restrict__ xw, const float* __restrict__ ai,
    const float* __restrict__ aj, const int* __restrict__ rowstart,
    const int* __restrict__ col, const float* __restrict__ b3, int N,
    float* __restrict__ out) {
  int t = blockIdx.x * 256 + threadIdx.x;
  int n = t >> 2;
  if (n >= N) return;
  int h = t & 3;
  int r0 = rowstart[n], r1 = rowstart[n + 1];
  float ain = ai[n * 4 + h];
  float smax = -1e30f;
  for (int e = r0; e < r1; ++e) {
    int s = clampN(col[e], N);
    smax = fmaxf(smax, aj[s * 4 + h]);
  }
  float m = ain + smax;
  m = (m > 0.f) ? m : 0.2f * m;
  float denom = 0.f, acc = 0.f;
  for (int e = r0; e < r1; ++e) {
    int s = clampN(col[e], N);
    float ev = ain + aj[s * 4 + h];
    ev = (ev > 0.f) ? ev : 0.2f * ev;
    float p = __expf(ev - m);
    denom += p;
    acc += p * xw[s * 4 + h];
  }
  float o = acc / denom;
  o += __shfl_xor(o, 1, 4);
  o += __shfl_xor(o, 2, 4);
  o *= 0.25f;
  if (h == 0) out[n] = o + b3[0];
}

extern "C" void kernel_launch(void* const* d_in, const int* in_sizes, int n_in,
                              void* d_out, int out_size, void* d_ws, size_t ws_size,
                              hipStream_t stream) {
  const float* X    = (const float*)d_in[0];
  const int*   ei   = (const int*)d_in[1];
  const float* W1   = (const float*)d_in[2];
  const float* att1 = (const float*)d_in[3];
  const float* b1   = (const float*)d_in[4];
  const float* W2   = (const float*)d_in[5];
  const float* att2 = (const float*)d_in[6];
  const float* b2   = (const float*)d_in[7];
  const float* W3   = (const float*)d_in[8];
  const float* att3 = (const float*)d_in[9];
  const float* b3   = (const float*)d_in[10];
  float* out = (float*)d_out;

  const int N  = in_sizes[0] / FDIM;   // 50000
  const int E  = in_sizes[1] / 2;      // 800000
  const int ET = E + N;

  // Workspace carve (16B-aligned). deg/fill alias xw's region: the CSR build
  // completes before the first GEMM writes xw.
  char* ws = (char*)d_ws;
  auto carve = [&](size_t bytes) {
    char* p = ws; ws += (bytes + 15) & ~(size_t)15; return p;
  };
  float* xw       = (float*)carve((size_t)N * 64 * 4);
  float* hfeat    = (float*)carve((size_t)N * 64 * 4);
  float* ai       = (float*)carve((size_t)N * 8 * 4);
  float* aj       = (float*)carve((size_t)N * 8 * 4);
  int*   rowstart = (int*)carve((size_t)(N + 1) * 4);
  int*   colidx   = (int*)carve((size_t)ET * 4);
  int*   stflag   = (int*)carve(16);
  size_t need = (size_t)(ws - (char*)d_ws);
  if (ws_size < need) return;  // diagnostic: stub-signature absmax => ws too small
  int* deg  = (int*)xw;        // aliases, used only during CSR build
  int* fill = (int*)(xw + N);

  const int edgeBlocks  = (ET + 255) / 256;
  const int nodeBlocks4 = (N + 3) / 4;
  const int laneBlocks4 = (N * 4 + 255) / 256;

  // ---- CSR build (once; shared by all 3 layers) ----
  detect_stride_kernel<<<1, 256, 0, stream>>>(ei, E, stflag);
  zero_int_kernel<<<(N + 255) / 256, 256, 0, stream>>>(deg, N);
  count_deg_kernel<<<edgeBlocks, 256, 0, stream>>>(ei, stflag, E, N, deg);
  scan_kernel<<<1, 1024, 0, stream>>>(deg, rowstart, fill, N, ET);
  scatter_kernel<<<edgeBlocks, 256, 0, stream>>>(ei, stflag, E, N, fill, colidx);

  // ---- layer 1 ----
  gemm_att64_kernel<<<nodeBlocks4, 256, 0, stream>>>(X, W1, att1, N, xw, ai, aj);
  gather64_kernel<<<nodeBlocks4, 256, 0, stream>>>(xw, ai, aj, rowstart, colidx,
                                                   b1, N, 1, hfeat);
  // ---- layer 2 ----
  gemm_att64_kernel<<<nodeBlocks4, 256, 0, stream>>>(hfeat, W2, att2, N, xw, ai, aj);
  gather64_kernel<<<nodeBlocks4, 256, 0, stream>>>(xw, ai, aj, rowstart, colidx,
                                                   b2, N, 1, hfeat);
  // ---- layer 3 ----
  gemm_att4_kernel<<<laneBlocks4, 256, 0, stream>>>(hfeat, W3, att3, N, xw, ai, aj);
  gather4_kernel<<<laneBlocks4, 256, 0, stream>>>(xw, ai, aj, rowstart, colidx,
                                                  b3, N, out);
}

// Round 4
// 558.794 us; speedup vs baseline: 1.1494x; 1.1494x over previous
//
#include <hip/hip_runtime.h>
#include <hip/hip_bf16.h>
#include <float.h>

// GAT, 3 layers: (8,8,concat) -> relu -> (8,8,concat) -> relu -> (4,1,mean)
// N=50000, E=800000 (+N self-loops).
// R3 -> R4 changes (theory: gather is latency-bound, two edge passes):
//  * per-layer GLOBAL max of a_j fused into the projection kernels
//    (wave reduce + ordered-uint atomicMax). Softmax only needs an upper
//    bound on the segment max: m = leaky(a_i + M_global) >= local emax and
//    the exp-shift cancels exactly in the ratio.
//  * gather kernels become SINGLE-PASS over edges (denom + weighted sum in
//    one loop, divide at end).
//  * gemm_att64 grid-strided (1024 blocks) so the 16KB W tile in LDS is
//    loaded once per block, not once per 4 nodes; x rows staged via LDS.

#define FDIM 64

__device__ __forceinline__ int clampN(int v, int N) {
  return ((unsigned)v >= (unsigned)N) ? 0 : v;
}
// order-preserving float<->uint for atomicMax on floats
__device__ __forceinline__ unsigned f2ord(float f) {
  unsigned u = __float_as_uint(f);
  return (u & 0x80000000u) ? ~u : (u | 0x80000000u);
}
__device__ __forceinline__ float ord2f(unsigned o) {
  return __uint_as_float((o & 0x80000000u) ? (o & 0x7FFFFFFFu) : ~o);
}

__global__ __launch_bounds__(256) void zero_init_kernel(
    int* __restrict__ deg, int n, unsigned* __restrict__ maxslot) {
  int i = blockIdx.x * 256 + threadIdx.x;
  if (i < n) deg[i] = 0;
  if (i < 4) maxslot[i] = 0u;  // floor of the ordered-uint encoding
}

// int64 upload => odd 32-bit words (high words of ids < 2^31) all zero.
__global__ __launch_bounds__(256) void detect_stride_kernel(
    const int* __restrict__ ei, int E, int* __restrict__ flag) {
  __shared__ int any;
  if (threadIdx.x == 0) any = 0;
  __syncthreads();
  int idx = 2 * threadIdx.x + 1;
  int v = (idx < 2 * E) ? ei[idx] : 0;
  if (v != 0) atomicOr(&any, 1);
  __syncthreads();
  if (threadIdx.x == 0) *flag = any ? 1 : 2;
}

__global__ __launch_bounds__(256) void count_deg_kernel(
    const int* __restrict__ ei, const int* __restrict__ flag, int E, int N,
    int* __restrict__ deg) {
  int st = *flag;
  int e = blockIdx.x * 256 + threadIdx.x;
  int ET = E + N;
  if (e >= ET) return;
  int dst = (e < E) ? clampN(ei[(size_t)st * (E + e)], N) : (e - E);
  atomicAdd(&deg[dst], 1);
}

__global__ __launch_bounds__(1024) void scan_kernel(
    const int* __restrict__ deg, int* __restrict__ rowstart,
    int* __restrict__ fill, int N, int total) {
  __shared__ int part[1024];
  int t = threadIdx.x;
  int chunk = (N + 1023) >> 10;
  int lo = t * chunk;
  int hi = lo + chunk; if (hi > N) hi = N;
  int s = 0;
  for (int i = lo; i < hi; ++i) s += deg[i];
  part[t] = s;
  __syncthreads();
  for (int off = 1; off < 1024; off <<= 1) {  // Hillis-Steele inclusive
    int v = (t >= off) ? part[t - off] : 0;
    __syncthreads();
    part[t] += v;
    __syncthreads();
  }
  int run = part[t] - s;  // exclusive base
  for (int i = lo; i < hi; ++i) {
    rowstart[i] = run;
    fill[i] = run;
    run += deg[i];
  }
  if (t == 0) rowstart[N] = total;
}

__global__ __launch_bounds__(256) void scatter_kernel(
    const int* __restrict__ ei, const int* __restrict__ flag, int E, int N,
    int* __restrict__ fill, int* __restrict__ col) {
  int st = *flag;
  int e = blockIdx.x * 256 + threadIdx.x;
  int ET = E + N;
  if (e >= ET) return;
  int src, dst;
  if (e < E) {
    src = clampN(ei[(size_t)st * e], N);
    dst = clampN(ei[(size_t)st * (E + e)], N);
  } else {
    src = e - E; dst = e - E;
  }
  int pos = atomicAdd(&fill[dst], 1);
  if ((unsigned)pos < (unsigned)ET) col[pos] = src;
}

// Layers 1-2 projection: xw = x@W (64x64) + per-node scores + global aj max.
// Grid-stride over node-quads; W staged in LDS once per block.
__global__ __launch_bounds__(256) void gemm_att64_kernel(
    const float* __restrict__ x, const float* __restrict__ W,
    const float* __restrict__ att, int N, float* __restrict__ xw,
    float* __restrict__ ai, float* __restrict__ aj,
    unsigned* __restrict__ maxslot) {
  __shared__ float Wl[64 * 64];
  __shared__ float xq[4 * 64];
  __shared__ float red[4];
  int tid = threadIdx.x;
  for (int i = tid; i < 64 * 64; i += 256) Wl[i] = W[i];
  int j = tid & 63;
  int g = tid >> 6;  // node-in-quad / wave id
  int h = j >> 3, c = j & 7;
  float attI = att[h * 16 + c];
  float attJ = att[h * 16 + 8 + c];
  float pmax = -FLT_MAX;
  int nquads = (N + 3) >> 2;
  for (int q = blockIdx.x; q < nquads; q += gridDim.x) {
    int n = q * 4 + g;
    __syncthreads();                      // protect xq reuse
    // stage 4 x-rows, coalesced: thread tid loads row g element j
    if (n < N) xq[g * 64 + j] = x[(size_t)n * 64 + j];
    __syncthreads();
    if (n >= N) continue;
    float acc = 0.f;
    #pragma unroll
    for (int k = 0; k < 64; ++k) acc += xq[g * 64 + k] * Wl[k * 64 + j];
    xw[(size_t)n * 64 + j] = acc;
    float pi = acc * attI;
    float pj = acc * attJ;
    #pragma unroll
    for (int off = 1; off < 8; off <<= 1) {
      pi += __shfl_xor(pi, off, 8);
      pj += __shfl_xor(pj, off, 8);
    }
    if (c == 0) {
      ai[n * 8 + h] = pi;
      aj[n * 8 + h] = pj;
    }
    pmax = fmaxf(pmax, pj);
  }
  // block-reduce pmax -> one atomicMax per block
  #pragma unroll
  for (int off = 1; off < 64; off <<= 1) pmax = fmaxf(pmax, __shfl_xor(pmax, off, 64));
  __syncthreads();
  if ((tid & 63) == 0) red[g] = pmax;
  __syncthreads();
  if (tid == 0) {
    float m = fmaxf(fmaxf(red[0], red[1]), fmaxf(red[2], red[3]));
    atomicMax(maxslot, f2ord(m));
  }
}

// Layer 3 projection: xw = x@W3 (64x4), H=4, C=1, + global aj max.
__global__ __launch_bounds__(256) void gemm_att4_kernel(
    const float* __restrict__ x, const float* __restrict__ W,
    const float* __restrict__ att, int N, float* __restrict__ xw,
    float* __restrict__ ai, float* __restrict__ aj,
    unsigned* __restrict__ maxslot) {
  __shared__ float red[4];
  int t = blockIdx.x * 256 + threadIdx.x;
  int n = t >> 2;
  int j = t & 3;
  float pj = -FLT_MAX;
  if (n < N) {
    const float* xr = x + (size_t)n * 64;
    float acc = 0.f;
    #pragma unroll
    for (int k = 0; k < 64; ++k) acc += xr[k] * W[k * 4 + j];
    xw[n * 4 + j] = acc;
    ai[n * 4 + j] = acc * att[j * 2];
    pj = acc * att[j * 2 + 1];
    aj[n * 4 + j] = pj;
  }
  float pmax = pj;
  #pragma unroll
  for (int off = 1; off < 64; off <<= 1) pmax = fmaxf(pmax, __shfl_xor(pmax, off, 64));
  if ((threadIdx.x & 63) == 0) red[threadIdx.x >> 6] = pmax;
  __syncthreads();
  if (threadIdx.x == 0) {
    float m = fmaxf(fmaxf(red[0], red[1]), fmaxf(red[2], red[3]));
    atomicMax(maxslot, f2ord(m));
  }
}

// Layers 1-2 aggregation, SINGLE PASS: block = 4 nodes x 64 lanes (f=h*8+c).
__global__ __launch_bounds__(256) void gather64_kernel(
    const float* __restrict__ xw, const float* __restrict__ ai,
    const float* __restrict__ aj, const int* __restrict__ rowstart,
    const int* __restrict__ col, const float* __restrict__ bias, int N,
    int relu, float* __restrict__ out, const unsigned* __restrict__ maxslot) {
  int n = blockIdx.x * 4 + (threadIdx.x >> 6);
  if (n >= N) return;
  float M = ord2f(*maxslot);
  int f = threadIdx.x & 63;
  int h = f >> 3;
  int r0 = rowstart[n], r1 = rowstart[n + 1];
  float ain = ai[n * 8 + h];
  float m = ain + M;                 // >= local max since M >= all aj
  m = (m > 0.f) ? m : 0.2f * m;      // leaky monotone => m >= local emax
  float denom = 0.f, acc = 0.f;
  for (int e = r0; e < r1; ++e) {
    int s = clampN(col[e], N);
    float ev = ain + aj[s * 8 + h];
    ev = (ev > 0.f) ? ev : 0.2f * ev;
    float p = __expf(ev - m);
    denom += p;                          // redundant across lanes sharing h
    acc += p * xw[(size_t)s * 64 + f];   // coalesced 256B row read
  }
  float o = acc / denom + bias[f];
  if (relu) o = fmaxf(o, 0.f);
  out[(size_t)n * 64 + f] = o;
}

// Layer 3 aggregation + head-mean + bias, SINGLE PASS. 4 lanes per node.
__global__ __launch_bounds__(256) void gather4_kernel(
    const float* __restrict__ xw, const float* __restrict__ ai,
    const float* __restrict__ aj, const int* __restrict__ rowstart,
    const int* __restrict__ col, const float* __restrict__ b3, int N,
    float* __restrict__ out, const unsigned* __restrict__ maxslot) {
  int t = blockIdx.x * 256 + threadIdx.x;
  int n = t >> 2;
  if (n >= N) return;
  float M = ord2f(*maxslot);
  int h = t & 3;
  int r0 = rowstart[n], r1 = rowstart[n + 1];
  float ain = ai[n * 4 + h];
  float m = ain + M;
  m = (m > 0.f) ? m : 0.2f * m;
  float denom = 0.f, acc = 0.f;
  for (int e = r0; e < r1; ++e) {
    int s = clampN(col[e], N);
    float ev = ain + aj[s * 4 + h];
    ev = (ev > 0.f) ? ev : 0.2f * ev;
    float p = __expf(ev - m);
    denom += p;
    acc += p * xw[s * 4 + h];
  }
  float o = acc / denom;
  o += __shfl_xor(o, 1, 4);
  o += __shfl_xor(o, 2, 4);
  o *= 0.25f;
  if (h == 0) out[n] = o + b3[0];
}

extern "C" void kernel_launch(void* const* d_in, const int* in_sizes, int n_in,
                              void* d_out, int out_size, void* d_ws, size_t ws_size,
                              hipStream_t stream) {
  const float* X    = (const float*)d_in[0];
  const int*   ei   = (const int*)d_in[1];
  const float* W1   = (const float*)d_in[2];
  const float* att1 = (const float*)d_in[3];
  const float* b1   = (const float*)d_in[4];
  const float* W2   = (const float*)d_in[5];
  const float* att2 = (const float*)d_in[6];
  const float* b2   = (const float*)d_in[7];
  const float* W3   = (const float*)d_in[8];
  const float* att3 = (const float*)d_in[9];
  const float* b3   = (const float*)d_in[10];
  float* out = (float*)d_out;

  const int N  = in_sizes[0] / FDIM;   // 50000
  const int E  = in_sizes[1] / 2;      // 800000
  const int ET = E + N;

  // workspace carve (16B aligned); deg/fill alias xw (CSR build precedes GEMM)
  char* ws = (char*)d_ws;
  auto carve = [&](size_t bytes) {
    char* p = ws; ws += (bytes + 15) & ~(size_t)15; return p;
  };
  float*    xw       = (float*)carve((size_t)N * 64 * 4);
  float*    hfeat    = (float*)carve((size_t)N * 64 * 4);
  float*    ai       = (float*)carve((size_t)N * 8 * 4);
  float*    aj       = (float*)carve((size_t)N * 8 * 4);
  int*      rowstart = (int*)carve((size_t)(N + 1) * 4);
  int*      colidx   = (int*)carve((size_t)ET * 4);
  int*      stflag   = (int*)carve(16);
  unsigned* maxslot  = (unsigned*)carve(16);   // [0..2]: per-layer global aj max
  size_t need = (size_t)(ws - (char*)d_ws);
  if (ws_size < need) return;
  int* deg  = (int*)xw;
  int* fill = (int*)(xw + N);

  const int edgeBlocks  = (ET + 255) / 256;
  const int nodeBlocks4 = (N + 3) / 4;
  const int laneBlocks4 = (N * 4 + 255) / 256;

  // ---- CSR build (once; shared by all 3 layers) ----
  detect_stride_kernel<<<1, 256, 0, stream>>>(ei, E, stflag);
  zero_init_kernel<<<(N + 255) / 256, 256, 0, stream>>>(deg, N, maxslot);
  count_deg_kernel<<<edgeBlocks, 256, 0, stream>>>(ei, stflag, E, N, deg);
  scan_kernel<<<1, 1024, 0, stream>>>(deg, rowstart, fill, N, ET);
  scatter_kernel<<<edgeBlocks, 256, 0, stream>>>(ei, stflag, E, N, fill, colidx);

  // ---- layer 1 ----
  gemm_att64_kernel<<<1024, 256, 0, stream>>>(X, W1, att1, N, xw, ai, aj, maxslot + 0);
  gather64_kernel<<<nodeBlocks4, 256, 0, stream>>>(xw, ai, aj, rowstart, colidx,
                                                   b1, N, 1, hfeat, maxslot + 0);
  // ---- layer 2 ----
  gemm_att64_kernel<<<1024, 256, 0, stream>>>(hfeat, W2, att2, N, xw, ai, aj, maxslot + 1);
  gather64_kernel<<<nodeBlocks4, 256, 0, stream>>>(xw, ai, aj, rowstart, colidx,
                                                   b2, N, 1, hfeat, maxslot + 1);
  // ---- layer 3 ----
  gemm_att4_kernel<<<laneBlocks4, 256, 0, stream>>>(hfeat, W3, att3, N, xw, ai, aj, maxslot + 2);
  gather4_kernel<<<laneBlocks4, 256, 0, stream>>>(xw, ai, aj, rowstart, colidx,
                                                  b3, N, out, maxslot + 2);
}

// Round 5
// 357.144 us; speedup vs baseline: 1.7984x; 1.5646x over previous
//
#include <hip/hip_runtime.h>
#include <hip/hip_bf16.h>
#include <float.h>

// GAT, 3 layers: (8,8,concat) -> relu -> (8,8,concat) -> relu -> (4,1,mean)
// N=50000, E=800000 (+N self-loops).
// R4 -> R5 changes:
//  * 1-block scan (111us, 0.14% occupancy, uncoalesced) -> 3-phase
//    multi-block scan (tile sums -> scan partials -> apply), coalesced.
//  * gather64/gather4 edge loops manually unrolled x4: batch the col/aj/xw
//    loads to quadruple memory-level parallelism (loops are latency-bound:
//    VALUBusy 41%, HBM 11%).

#define FDIM 64
#define SCAN_TILE 256

__device__ __forceinline__ int clampN(int v, int N) {
  return ((unsigned)v >= (unsigned)N) ? 0 : v;
}
// order-preserving float<->uint for atomicMax on floats
__device__ __forceinline__ unsigned f2ord(float f) {
  unsigned u = __float_as_uint(f);
  return (u & 0x80000000u) ? ~u : (u | 0x80000000u);
}
__device__ __forceinline__ float ord2f(unsigned o) {
  return __uint_as_float((o & 0x80000000u) ? (o & 0x7FFFFFFFu) : ~o);
}

// zero deg + maxslots; block 0 also detects edge_index word stride
// (int64 upload => odd 32-bit words all zero since ids < 2^31).
__global__ __launch_bounds__(256) void init_kernel(
    const int* __restrict__ ei, int E, int* __restrict__ deg, int N,
    unsigned* __restrict__ maxslot, int* __restrict__ flag) {
  int i = blockIdx.x * 256 + threadIdx.x;
  if (i < N) deg[i] = 0;
  if (i < 4) maxslot[i] = 0u;
  if (blockIdx.x == 0) {
    __shared__ int any;
    if (threadIdx.x == 0) any = 0;
    __syncthreads();
    int idx = 2 * threadIdx.x + 1;
    int v = (idx < 2 * E) ? ei[idx] : 0;
    if (v != 0) atomicOr(&any, 1);
    __syncthreads();
    if (threadIdx.x == 0) *flag = any ? 1 : 2;
  }
}

__global__ __launch_bounds__(256) void count_deg_kernel(
    const int* __restrict__ ei, const int* __restrict__ flag, int E, int N,
    int* __restrict__ deg) {
  int st = *flag;
  int e = blockIdx.x * 256 + threadIdx.x;
  int ET = E + N;
  if (e >= ET) return;
  int dst = (e < E) ? clampN(ei[(size_t)st * (E + e)], N) : (e - E);
  atomicAdd(&deg[dst], 1);
}

// ---- 3-phase coalesced scan of deg[0..N) -> rowstart (exclusive) ----
__global__ __launch_bounds__(SCAN_TILE) void scan_partial_kernel(
    const int* __restrict__ deg, int N, int* __restrict__ bsum) {
  __shared__ int part[SCAN_TILE];
  int i = blockIdx.x * SCAN_TILE + threadIdx.x;
  int v = (i < N) ? deg[i] : 0;
  part[threadIdx.x] = v;
  __syncthreads();
  for (int off = 1; off < SCAN_TILE; off <<= 1) {
    int t = (threadIdx.x >= off) ? part[threadIdx.x - off] : 0;
    __syncthreads();
    part[threadIdx.x] += t;
    __syncthreads();
  }
  if (threadIdx.x == SCAN_TILE - 1) bsum[blockIdx.x] = part[SCAN_TILE - 1];
}

__global__ __launch_bounds__(1024) void scan_bsum_kernel(
    int* __restrict__ bsum, int nb, int* __restrict__ rowstartN, int N) {
  __shared__ int part[1024];
  int t = threadIdx.x;
  int v = (t < nb) ? bsum[t] : 0;
  part[t] = v;
  __syncthreads();
  for (int off = 1; off < 1024; off <<= 1) {
    int x = (t >= off) ? part[t - off] : 0;
    __syncthreads();
    part[t] += x;
    __syncthreads();
  }
  if (t < nb) bsum[t] = part[t] - v;         // exclusive block offset
  if (t == 1023) rowstartN[N] = part[1023];  // total
}

__global__ __launch_bounds__(SCAN_TILE) void scan_apply_kernel(
    const int* __restrict__ deg, int N, const int* __restrict__ bsum,
    int* __restrict__ rowstart, int* __restrict__ fill) {
  __shared__ int part[SCAN_TILE];
  int i = blockIdx.x * SCAN_TILE + threadIdx.x;
  int v = (i < N) ? deg[i] : 0;
  part[threadIdx.x] = v;
  __syncthreads();
  for (int off = 1; off < SCAN_TILE; off <<= 1) {
    int t = (threadIdx.x >= off) ? part[threadIdx.x - off] : 0;
    __syncthreads();
    part[threadIdx.x] += t;
    __syncthreads();
  }
  if (i < N) {
    int excl = bsum[blockIdx.x] + part[threadIdx.x] - v;
    rowstart[i] = excl;
    fill[i] = excl;
  }
}

__global__ __launch_bounds__(256) void scatter_kernel(
    const int* __restrict__ ei, const int* __restrict__ flag, int E, int N,
    int* __restrict__ fill, int* __restrict__ col) {
  int st = *flag;
  int e = blockIdx.x * 256 + threadIdx.x;
  int ET = E + N;
  if (e >= ET) return;
  int src, dst;
  if (e < E) {
    src = clampN(ei[(size_t)st * e], N);
    dst = clampN(ei[(size_t)st * (E + e)], N);
  } else {
    src = e - E; dst = e - E;
  }
  int pos = atomicAdd(&fill[dst], 1);
  if ((unsigned)pos < (unsigned)ET) col[pos] = src;
}

// Layers 1-2 projection: xw = x@W (64x64) + per-node scores + global aj max.
// Grid-stride; W staged in LDS once per block.
__global__ __launch_bounds__(256) void gemm_att64_kernel(
    const float* __restrict__ x, const float* __restrict__ W,
    const float* __restrict__ att, int N, float* __restrict__ xw,
    float* __restrict__ ai, float* __restrict__ aj,
    unsigned* __restrict__ maxslot) {
  __shared__ float Wl[64 * 64];
  __shared__ float xq[4 * 64];
  __shared__ float red[4];
  int tid = threadIdx.x;
  for (int i = tid; i < 64 * 64; i += 256) Wl[i] = W[i];
  int j = tid & 63;
  int g = tid >> 6;
  int h = j >> 3, c = j & 7;
  float attI = att[h * 16 + c];
  float attJ = att[h * 16 + 8 + c];
  float pmax = -FLT_MAX;
  int nquads = (N + 3) >> 2;
  for (int q = blockIdx.x; q < nquads; q += gridDim.x) {
    int n = q * 4 + g;
    __syncthreads();
    if (n < N) xq[g * 64 + j] = x[(size_t)n * 64 + j];
    __syncthreads();
    if (n >= N) continue;
    float acc = 0.f;
    #pragma unroll
    for (int k = 0; k < 64; ++k) acc += xq[g * 64 + k] * Wl[k * 64 + j];
    xw[(size_t)n * 64 + j] = acc;
    float pi = acc * attI;
    float pj = acc * attJ;
    #pragma unroll
    for (int off = 1; off < 8; off <<= 1) {
      pi += __shfl_xor(pi, off, 8);
      pj += __shfl_xor(pj, off, 8);
    }
    if (c == 0) {
      ai[n * 8 + h] = pi;
      aj[n * 8 + h] = pj;
    }
    pmax = fmaxf(pmax, pj);
  }
  #pragma unroll
  for (int off = 1; off < 64; off <<= 1) pmax = fmaxf(pmax, __shfl_xor(pmax, off, 64));
  __syncthreads();
  if ((tid & 63) == 0) red[g] = pmax;
  __syncthreads();
  if (tid == 0) {
    float m = fmaxf(fmaxf(red[0], red[1]), fmaxf(red[2], red[3]));
    atomicMax(maxslot, f2ord(m));
  }
}

// Layer 3 projection: xw = x@W3 (64x4), H=4, C=1, + global aj max.
__global__ __launch_bounds__(256) void gemm_att4_kernel(
    const float* __restrict__ x, const float* __restrict__ W,
    const float* __restrict__ att, int N, float* __restrict__ xw,
    float* __restrict__ ai, float* __restrict__ aj,
    unsigned* __restrict__ maxslot) {
  __shared__ float red[4];
  int t = blockIdx.x * 256 + threadIdx.x;
  int n = t >> 2;
  int j = t & 3;
  float pj = -FLT_MAX;
  if (n < N) {
    const float* xr = x + (size_t)n * 64;
    float acc = 0.f;
    #pragma unroll
    for (int k = 0; k < 64; ++k) acc += xr[k] * W[k * 4 + j];
    xw[n * 4 + j] = acc;
    ai[n * 4 + j] = acc * att[j * 2];
    pj = acc * att[j * 2 + 1];
    aj[n * 4 + j] = pj;
  }
  float pmax = pj;
  #pragma unroll
  for (int off = 1; off < 64; off <<= 1) pmax = fmaxf(pmax, __shfl_xor(pmax, off, 64));
  if ((threadIdx.x & 63) == 0) red[threadIdx.x >> 6] = pmax;
  __syncthreads();
  if (threadIdx.x == 0) {
    float m = fmaxf(fmaxf(red[0], red[1]), fmaxf(red[2], red[3]));
    atomicMax(maxslot, f2ord(m));
  }
}

// Layers 1-2 aggregation, single pass, edge loop unrolled x4 for MLP.
// Block = 4 nodes x 64 lanes (lane = f = h*8+c).
__global__ __launch_bounds__(256) void gather64_kernel(
    const float* __restrict__ xw, const float* __restrict__ ai,
    const float* __restrict__ aj, const int* __restrict__ rowstart,
    const int* __restrict__ col, const float* __restrict__ bias, int N,
    int relu, float* __restrict__ out, const unsigned* __restrict__ maxslot) {
  int n = blockIdx.x * 4 + (threadIdx.x >> 6);
  if (n >= N) return;
  float M = ord2f(*maxslot);
  int f = threadIdx.x & 63;
  int h = f >> 3;
  int r0 = rowstart[n], r1 = rowstart[n + 1];
  float ain = ai[n * 8 + h];
  float m = ain + M;                 // >= local max (M >= all aj)
  m = (m > 0.f) ? m : 0.2f * m;      // leaky monotone => m >= local emax
  float denom = 0.f, acc = 0.f;
  int e = r0;
  for (; e + 4 <= r1; e += 4) {
    int s0 = clampN(col[e + 0], N);
    int s1 = clampN(col[e + 1], N);
    int s2 = clampN(col[e + 2], N);
    int s3 = clampN(col[e + 3], N);
    float a0 = aj[s0 * 8 + h], a1 = aj[s1 * 8 + h];
    float a2 = aj[s2 * 8 + h], a3 = aj[s3 * 8 + h];
    float x0 = xw[(size_t)s0 * 64 + f], x1 = xw[(size_t)s1 * 64 + f];
    float x2 = xw[(size_t)s2 * 64 + f], x3 = xw[(size_t)s3 * 64 + f];
    float e0 = ain + a0; e0 = (e0 > 0.f) ? e0 : 0.2f * e0;
    float e1 = ain + a1; e1 = (e1 > 0.f) ? e1 : 0.2f * e1;
    float e2 = ain + a2; e2 = (e2 > 0.f) ? e2 : 0.2f * e2;
    float e3 = ain + a3; e3 = (e3 > 0.f) ? e3 : 0.2f * e3;
    float p0 = __expf(e0 - m), p1 = __expf(e1 - m);
    float p2 = __expf(e2 - m), p3 = __expf(e3 - m);
    denom += (p0 + p1) + (p2 + p3);
    acc += p0 * x0; acc += p1 * x1; acc += p2 * x2; acc += p3 * x3;
  }
  for (; e < r1; ++e) {
    int s = clampN(col[e], N);
    float ev = ain + aj[s * 8 + h];
    ev = (ev > 0.f) ? ev : 0.2f * ev;
    float p = __expf(ev - m);
    denom += p;
    acc += p * xw[(size_t)s * 64 + f];
  }
  float o = acc / denom + bias[f];
  if (relu) o = fmaxf(o, 0.f);
  out[(size_t)n * 64 + f] = o;
}

// Layer 3 aggregation + head-mean + bias, single pass, unrolled x4.
__global__ __launch_bounds__(256) void gather4_kernel(
    const float* __restrict__ xw, const float* __restrict__ ai,
    const float* __restrict__ aj, const int* __restrict__ rowstart,
    const int* __restrict__ col, const float* __restrict__ b3, int N,
    float* __restrict__ out, const unsigned* __restrict__ maxslot) {
  int t = blockIdx.x * 256 + threadIdx.x;
  int n = t >> 2;
  if (n >= N) return;
  float M = ord2f(*maxslot);
  int h = t & 3;
  int r0 = rowstart[n], r1 = rowstart[n + 1];
  float ain = ai[n * 4 + h];
  float m = ain + M;
  m = (m > 0.f) ? m : 0.2f * m;
  float denom = 0.f, acc = 0.f;
  int e = r0;
  for (; e + 4 <= r1; e += 4) {
    int s0 = clampN(col[e + 0], N);
    int s1 = clampN(col[e + 1], N);
    int s2 = clampN(col[e + 2], N);
    int s3 = clampN(col[e + 3], N);
    float a0 = aj[s0 * 4 + h], a1 = aj[s1 * 4 + h];
    float a2 = aj[s2 * 4 + h], a3 = aj[s3 * 4 + h];
    float x0 = xw[s0 * 4 + h], x1 = xw[s1 * 4 + h];
    float x2 = xw[s2 * 4 + h], x3 = xw[s3 * 4 + h];
    float e0 = ain + a0; e0 = (e0 > 0.f) ? e0 : 0.2f * e0;
    float e1 = ain + a1; e1 = (e1 > 0.f) ? e1 : 0.2f * e1;
    float e2 = ain + a2; e2 = (e2 > 0.f) ? e2 : 0.2f * e2;
    float e3 = ain + a3; e3 = (e3 > 0.f) ? e3 : 0.2f * e3;
    float p0 = __expf(e0 - m), p1 = __expf(e1 - m);
    float p2 = __expf(e2 - m), p3 = __expf(e3 - m);
    denom += (p0 + p1) + (p2 + p3);
    acc += p0 * x0; acc += p1 * x1; acc += p2 * x2; acc += p3 * x3;
  }
  for (; e < r1; ++e) {
    int s = clampN(col[e], N);
    float ev = ain + aj[s * 4 + h];
    ev = (ev > 0.f) ? ev : 0.2f * ev;
    float p = __expf(ev - m);
    denom += p;
    acc += p * xw[s * 4 + h];
  }
  float o = acc / denom;
  o += __shfl_xor(o, 1, 4);
  o += __shfl_xor(o, 2, 4);
  o *= 0.25f;
  if (h == 0) out[n] = o + b3[0];
}

extern "C" void kernel_launch(void* const* d_in, const int* in_sizes, int n_in,
                              void* d_out, int out_size, void* d_ws, size_t ws_size,
                              hipStream_t stream) {
  const float* X    = (const float*)d_in[0];
  const int*   ei   = (const int*)d_in[1];
  const float* W1   = (const float*)d_in[2];
  const float* att1 = (const float*)d_in[3];
  const float* b1   = (const float*)d_in[4];
  const float* W2   = (const float*)d_in[5];
  const float* att2 = (const float*)d_in[6];
  const float* b2   = (const float*)d_in[7];
  const float* W3   = (const float*)d_in[8];
  const float* att3 = (const float*)d_in[9];
  const float* b3   = (const float*)d_in[10];
  float* out = (float*)d_out;

  const int N  = in_sizes[0] / FDIM;   // 50000
  const int E  = in_sizes[1] / 2;      // 800000
  const int ET = E + N;
  const int nb = (N + SCAN_TILE - 1) / SCAN_TILE;  // scan blocks (196)

  char* ws = (char*)d_ws;
  auto carve = [&](size_t bytes) {
    char* p = ws; ws += (bytes + 15) & ~(size_t)15; return p;
  };
  float*    xw       = (float*)carve((size_t)N * 64 * 4);
  float*    hfeat    = (float*)carve((size_t)N * 64 * 4);
  float*    ai       = (float*)carve((size_t)N * 8 * 4);
  float*    aj       = (float*)carve((size_t)N * 8 * 4);
  int*      rowstart = (int*)carve((size_t)(N + 1) * 4);
  int*      colidx   = (int*)carve((size_t)ET * 4);
  int*      stflag   = (int*)carve(16);
  unsigned* maxslot  = (unsigned*)carve(16);
  int*      bsum     = (int*)carve((size_t)((nb + 1023) & ~1023) * 4);
  size_t need = (size_t)(ws - (char*)d_ws);
  if (ws_size < need) return;
  int* deg  = (int*)xw;   // alias: CSR build precedes first GEMM write
  int* fill = (int*)(xw + N);

  const int edgeBlocks  = (ET + 255) / 256;
  const int nodeBlocks4 = (N + 3) / 4;
  const int laneBlocks4 = (N * 4 + 255) / 256;

  // ---- CSR build (once; shared by all 3 layers) ----
  init_kernel<<<(N + 255) / 256, 256, 0, stream>>>(ei, E, deg, N, maxslot, stflag);
  count_deg_kernel<<<edgeBlocks, 256, 0, stream>>>(ei, stflag, E, N, deg);
  scan_partial_kernel<<<nb, SCAN_TILE, 0, stream>>>(deg, N, bsum);
  scan_bsum_kernel<<<1, 1024, 0, stream>>>(bsum, nb, rowstart, N);
  scan_apply_kernel<<<nb, SCAN_TILE, 0, stream>>>(deg, N, bsum, rowstart, fill);
  scatter_kernel<<<edgeBlocks, 256, 0, stream>>>(ei, stflag, E, N, fill, colidx);

  // ---- layer 1 ----
  gemm_att64_kernel<<<1024, 256, 0, stream>>>(X, W1, att1, N, xw, ai, aj, maxslot + 0);
  gather64_kernel<<<nodeBlocks4, 256, 0, stream>>>(xw, ai, aj, rowstart, colidx,
                                                   b1, N, 1, hfeat, maxslot + 0);
  // ---- layer 2 ----
  gemm_att64_kernel<<<1024, 256, 0, stream>>>(hfeat, W2, att2, N, xw, ai, aj, maxslot + 1);
  gather64_kernel<<<nodeBlocks4, 256, 0, stream>>>(xw, ai, aj, rowstart, colidx,
                                                   b2, N, 1, hfeat, maxslot + 1);
  // ---- layer 3 ----
  gemm_att4_kernel<<<laneBlocks4, 256, 0, stream>>>(hfeat, W3, att3, N, xw, ai, aj, maxslot + 2);
  gather4_kernel<<<laneBlocks4, 256, 0, stream>>>(xw, ai, aj, rowstart, colidx,
                                                  b3, N, out, maxslot + 2);
}

// Round 6
// 310.291 us; speedup vs baseline: 2.0699x; 1.1510x over previous
//
#include <hip/hip_runtime.h>
#include <hip/hip_bf16.h>
#include <float.h>

// GAT, 3 layers: (8,8,concat) -> relu -> (8,8,concat) -> relu -> (4,1,mean)
// N=50000, E=800000 (+N self-loops).
// R5 -> R6: CSR build rewritten as bucketed counting sort.
//   scatter_kernel was 57us: 850K random 4B stores -> 54.6MB write-allocate
//   traffic (64B/line) + 850K serialized device atomics; count_deg similar.
//   New pipeline: hist(LDS) -> bucket scan -> binscatter (per-block bucket
//   reservations, contiguous per-bucket streams) -> bucketbuild (per-bucket
//   block: LDS count/scan/cursor scatter within a ~17KB L2-local window).
// Gather/GEMM kernels unchanged from R5 (single-pass softmax w/ global-max
// bound, x4 unrolled edge loops).

#define FDIM 64
#define BSHIFT 7                 // 128 nodes per bucket
#define BNODES (1 << BSHIFT)
#define BINCH 8192               // edges per binscatter block

__device__ __forceinline__ int clampN(int v, int N) {
  return ((unsigned)v >= (unsigned)N) ? 0 : v;
}
__device__ __forceinline__ unsigned f2ord(float f) {
  unsigned u = __float_as_uint(f);
  return (u & 0x80000000u) ? ~u : (u | 0x80000000u);
}
__device__ __forceinline__ float ord2f(unsigned o) {
  return __uint_as_float((o & 0x80000000u) ? (o & 0x7FFFFFFFu) : ~o);
}

// zero bucketCount + maxslots; block 0 detects edge_index word stride
// (int64 upload => odd 32-bit words all zero since ids < 2^31).
__global__ __launch_bounds__(256) void init_kernel(
    const int* __restrict__ ei, int E, int* __restrict__ bucketCount, int NB,
    unsigned* __restrict__ maxslot, int* __restrict__ flag) {
  int i = blockIdx.x * 256 + threadIdx.x;
  if (i < NB) bucketCount[i] = 0;
  if (i < 4) maxslot[i] = 0u;
  if (blockIdx.x == 0) {
    __shared__ int any;
    if (threadIdx.x == 0) any = 0;
    __syncthreads();
    int idx = 2 * threadIdx.x + 1;
    int v = (idx < 2 * E) ? ei[idx] : 0;
    if (v != 0) atomicOr(&any, 1);
    __syncthreads();
    if (threadIdx.x == 0) *flag = any ? 1 : 2;
  }
}

// coarse histogram of dst buckets (LDS-accumulated, few global atomics)
__global__ __launch_bounds__(256) void hist_kernel(
    const int* __restrict__ ei, const int* __restrict__ flag, int E, int N,
    int NB, int* __restrict__ bucketCount) {
  __shared__ int hist[512];
  int st = *flag;
  for (int i = threadIdx.x; i < NB; i += 256) hist[i] = 0;
  __syncthreads();
  int ET = E + N;
  for (int e = blockIdx.x * 256 + threadIdx.x; e < ET; e += gridDim.x * 256) {
    int dst = (e < E) ? clampN(ei[(size_t)st * (E + e)], N) : (e - E);
    atomicAdd(&hist[dst >> BSHIFT], 1);
  }
  __syncthreads();
  for (int i = threadIdx.x; i < NB; i += 256)
    if (hist[i]) atomicAdd(&bucketCount[i], hist[i]);
}

// 1-block scan of NB (<=512) bucket counts -> bucketBase (excl), fill=base
__global__ __launch_bounds__(512) void bucket_scan_kernel(
    const int* __restrict__ bucketCount, int NB, int* __restrict__ bucketBase,
    int* __restrict__ bucketFill, int* __restrict__ rowstart, int N, int ET) {
  __shared__ int s[512];
  int t = threadIdx.x;
  int v = (t < NB) ? bucketCount[t] : 0;
  s[t] = v;
  __syncthreads();
  for (int off = 1; off < 512; off <<= 1) {
    int x = (t >= off) ? s[t - off] : 0;
    __syncthreads();
    s[t] += x;
    __syncthreads();
  }
  if (t < NB) {
    int excl = s[t] - v;
    bucketBase[t] = excl;
    bucketFill[t] = excl;
  }
  if (t == 0) {
    bucketBase[NB] = s[511];  // == ET
    rowstart[N] = ET;
  }
}

// each block owns BINCH contiguous edges: LDS hist -> per-bucket global
// reservation -> write (src,dst) pairs into contiguous per-bucket streams
__global__ __launch_bounds__(256) void binscatter_kernel(
    const int* __restrict__ ei, const int* __restrict__ flag, int E, int N,
    int NB, int* __restrict__ bucketFill, int2* __restrict__ pairbuf, int ET) {
  __shared__ int hist[512];
  __shared__ int cursor[512];
  int st = *flag;
  int e0 = blockIdx.x * BINCH;
  int e1 = min(e0 + BINCH, ET);
  for (int i = threadIdx.x; i < NB; i += 256) hist[i] = 0;
  __syncthreads();
  for (int e = e0 + threadIdx.x; e < e1; e += 256) {
    int dst = (e < E) ? clampN(ei[(size_t)st * (E + e)], N) : (e - E);
    atomicAdd(&hist[dst >> BSHIFT], 1);
  }
  __syncthreads();
  for (int i = threadIdx.x; i < NB; i += 256)
    cursor[i] = hist[i] ? atomicAdd(&bucketFill[i], hist[i]) : 0;
  __syncthreads();
  for (int e = e0 + threadIdx.x; e < e1; e += 256) {
    int src, dst;
    if (e < E) {
      src = clampN(ei[(size_t)st * e], N);
      dst = clampN(ei[(size_t)st * (E + e)], N);
    } else {
      src = e - E; dst = e - E;
    }
    int pos = atomicAdd(&cursor[dst >> BSHIFT], 1);
    if ((unsigned)pos < (unsigned)ET) pairbuf[pos] = make_int2(src, dst);
  }
}

// one block per bucket: local degree count -> LDS scan -> rowstart; then
// cursor-scatter col within the bucket's contiguous edge range (L2-local)
__global__ __launch_bounds__(256) void bucketbuild_kernel(
    const int2* __restrict__ pairbuf, const int* __restrict__ bucketBase,
    int N, int ET, int* __restrict__ rowstart, int* __restrict__ col) {
  __shared__ int s[BNODES];
  int b = blockIdx.x;
  int t = threadIdx.x;
  int base = bucketBase[b], end = bucketBase[b + 1];
  int n0 = b << BSHIFT;
  int nn = min(BNODES, N - n0);
  if (t < BNODES) s[t] = 0;
  __syncthreads();
  for (int e = base + t; e < end; e += 256) {
    int li = pairbuf[e].y - n0;
    li = (li < 0) ? 0 : (li > BNODES - 1 ? BNODES - 1 : li);
    atomicAdd(&s[li], 1);
  }
  __syncthreads();
  int myd = (t < BNODES) ? s[t] : 0;
  for (int off = 1; off < BNODES; off <<= 1) {
    int v = (t >= off && t < BNODES) ? s[t - off] : 0;
    __syncthreads();
    if (t < BNODES) s[t] += v;
    __syncthreads();
  }
  int excl = (t < BNODES) ? (s[t] - myd) : 0;
  if (t < nn) rowstart[n0 + t] = base + excl;
  __syncthreads();
  if (t < BNODES) s[t] = excl;  // cursors
  __syncthreads();
  for (int e = base + t; e < end; e += 256) {
    int2 p = pairbuf[e];
    int li = p.y - n0;
    li = (li < 0) ? 0 : (li > BNODES - 1 ? BNODES - 1 : li);
    int pos = base + atomicAdd(&s[li], 1);
    if ((unsigned)pos < (unsigned)ET) col[pos] = p.x;
  }
}

// Layers 1-2 projection: xw = x@W (64x64) + per-node scores + global aj max.
__global__ __launch_bounds__(256) void gemm_att64_kernel(
    const float* __restrict__ x, const float* __restrict__ W,
    const float* __restrict__ att, int N, float* __restrict__ xw,
    float* __restrict__ ai, float* __restrict__ aj,
    unsigned* __restrict__ maxslot) {
  __shared__ float Wl[64 * 64];
  __shared__ float xq[4 * 64];
  __shared__ float red[4];
  int tid = threadIdx.x;
  for (int i = tid; i < 64 * 64; i += 256) Wl[i] = W[i];
  int j = tid & 63;
  int g = tid >> 6;
  int h = j >> 3, c = j & 7;
  float attI = att[h * 16 + c];
  float attJ = att[h * 16 + 8 + c];
  float pmax = -FLT_MAX;
  int nquads = (N + 3) >> 2;
  for (int q = blockIdx.x; q < nquads; q += gridDim.x) {
    int n = q * 4 + g;
    __syncthreads();
    if (n < N) xq[g * 64 + j] = x[(size_t)n * 64 + j];
    __syncthreads();
    if (n >= N) continue;
    float acc = 0.f;
    #pragma unroll
    for (int k = 0; k < 64; ++k) acc += xq[g * 64 + k] * Wl[k * 64 + j];
    xw[(size_t)n * 64 + j] = acc;
    float pi = acc * attI;
    float pj = acc * attJ;
    #pragma unroll
    for (int off = 1; off < 8; off <<= 1) {
      pi += __shfl_xor(pi, off, 8);
      pj += __shfl_xor(pj, off, 8);
    }
    if (c == 0) {
      ai[n * 8 + h] = pi;
      aj[n * 8 + h] = pj;
    }
    pmax = fmaxf(pmax, pj);
  }
  #pragma unroll
  for (int off = 1; off < 64; off <<= 1) pmax = fmaxf(pmax, __shfl_xor(pmax, off, 64));
  __syncthreads();
  if ((tid & 63) == 0) red[g] = pmax;
  __syncthreads();
  if (tid == 0) {
    float m = fmaxf(fmaxf(red[0], red[1]), fmaxf(red[2], red[3]));
    atomicMax(maxslot, f2ord(m));
  }
}

// Layer 3 projection: xw = x@W3 (64x4), H=4, C=1, + global aj max.
__global__ __launch_bounds__(256) void gemm_att4_kernel(
    const float* __restrict__ x, const float* __restrict__ W,
    const float* __restrict__ att, int N, float* __restrict__ xw,
    float* __restrict__ ai, float* __restrict__ aj,
    unsigned* __restrict__ maxslot) {
  __shared__ float red[4];
  int t = blockIdx.x * 256 + threadIdx.x;
  int n = t >> 2;
  int j = t & 3;
  float pj = -FLT_MAX;
  if (n < N) {
    const float* xr = x + (size_t)n * 64;
    float acc = 0.f;
    #pragma unroll
    for (int k = 0; k < 64; ++k) acc += xr[k] * W[k * 4 + j];
    xw[n * 4 + j] = acc;
    ai[n * 4 + j] = acc * att[j * 2];
    pj = acc * att[j * 2 + 1];
    aj[n * 4 + j] = pj;
  }
  float pmax = pj;
  #pragma unroll
  for (int off = 1; off < 64; off <<= 1) pmax = fmaxf(pmax, __shfl_xor(pmax, off, 64));
  if ((threadIdx.x & 63) == 0) red[threadIdx.x >> 6] = pmax;
  __syncthreads();
  if (threadIdx.x == 0) {
    float m = fmaxf(fmaxf(red[0], red[1]), fmaxf(red[2], red[3]));
    atomicMax(maxslot, f2ord(m));
  }
}

// Layers 1-2 aggregation, single pass, unrolled x4. 4 nodes x 64 lanes.
__global__ __launch_bounds__(256) void gather64_kernel(
    const float* __restrict__ xw, const float* __restrict__ ai,
    const float* __restrict__ aj, const int* __restrict__ rowstart,
    const int* __restrict__ col, const float* __restrict__ bias, int N,
    int relu, float* __restrict__ out, const unsigned* __restrict__ maxslot) {
  int n = blockIdx.x * 4 + (threadIdx.x >> 6);
  if (n >= N) return;
  float M = ord2f(*maxslot);
  int f = threadIdx.x & 63;
  int h = f >> 3;
  int r0 = rowstart[n], r1 = rowstart[n + 1];
  float ain = ai[n * 8 + h];
  float m = ain + M;                 // >= local max (M >= all aj)
  m = (m > 0.f) ? m : 0.2f * m;      // leaky monotone => m >= local emax
  float denom = 0.f, acc = 0.f;
  int e = r0;
  for (; e + 4 <= r1; e += 4) {
    int s0 = clampN(col[e + 0], N);
    int s1 = clampN(col[e + 1], N);
    int s2 = clampN(col[e + 2], N);
    int s3 = clampN(col[e + 3], N);
    float a0 = aj[s0 * 8 + h], a1 = aj[s1 * 8 + h];
    float a2 = aj[s2 * 8 + h], a3 = aj[s3 * 8 + h];
    float x0 = xw[(size_t)s0 * 64 + f], x1 = xw[(size_t)s1 * 64 + f];
    float x2 = xw[(size_t)s2 * 64 + f], x3 = xw[(size_t)s3 * 64 + f];
    float e0 = ain + a0; e0 = (e0 > 0.f) ? e0 : 0.2f * e0;
    float e1 = ain + a1; e1 = (e1 > 0.f) ? e1 : 0.2f * e1;
    float e2 = ain + a2; e2 = (e2 > 0.f) ? e2 : 0.2f * e2;
    float e3 = ain + a3; e3 = (e3 > 0.f) ? e3 : 0.2f * e3;
    float p0 = __expf(e0 - m), p1 = __expf(e1 - m);
    float p2 = __expf(e2 - m), p3 = __expf(e3 - m);
    denom += (p0 + p1) + (p2 + p3);
    acc += p0 * x0; acc += p1 * x1; acc += p2 * x2; acc += p3 * x3;
  }
  for (; e < r1; ++e) {
    int s = clampN(col[e], N);
    float ev = ain + aj[s * 8 + h];
    ev = (ev > 0.f) ? ev : 0.2f * ev;
    float p = __expf(ev - m);
    denom += p;
    acc += p * xw[(size_t)s * 64 + f];
  }
  float o = acc / denom + bias[f];
  if (relu) o = fmaxf(o, 0.f);
  out[(size_t)n * 64 + f] = o;
}

// Layer 3 aggregation + head-mean + bias, single pass, unrolled x4.
__global__ __launch_bounds__(256) void gather4_kernel(
    const float* __restrict__ xw, const float* __restrict__ ai,
    const float* __restrict__ aj, const int* __restrict__ rowstart,
    const int* __restrict__ col, const float* __restrict__ b3, int N,
    float* __restrict__ out, const unsigned* __restrict__ maxslot) {
  int t = blockIdx.x * 256 + threadIdx.x;
  int n = t >> 2;
  if (n >= N) return;
  float M = ord2f(*maxslot);
  int h = t & 3;
  int r0 = rowstart[n], r1 = rowstart[n + 1];
  float ain = ai[n * 4 + h];
  float m = ain + M;
  m = (m > 0.f) ? m : 0.2f * m;
  float denom = 0.f, acc = 0.f;
  int e = r0;
  for (; e + 4 <= r1; e += 4) {
    int s0 = clampN(col[e + 0], N);
    int s1 = clampN(col[e + 1], N);
    int s2 = clampN(col[e + 2], N);
    int s3 = clampN(col[e + 3], N);
    float a0 = aj[s0 * 4 + h], a1 = aj[s1 * 4 + h];
    float a2 = aj[s2 * 4 + h], a3 = aj[s3 * 4 + h];
    float x0 = xw[s0 * 4 + h], x1 = xw[s1 * 4 + h];
    float x2 = xw[s2 * 4 + h], x3 = xw[s3 * 4 + h];
    float e0 = ain + a0; e0 = (e0 > 0.f) ? e0 : 0.2f * e0;
    float e1 = ain + a1; e1 = (e1 > 0.f) ? e1 : 0.2f * e1;
    float e2 = ain + a2; e2 = (e2 > 0.f) ? e2 : 0.2f * e2;
    float e3 = ain + a3; e3 = (e3 > 0.f) ? e3 : 0.2f * e3;
    float p0 = __expf(e0 - m), p1 = __expf(e1 - m);
    float p2 = __expf(e2 - m), p3 = __expf(e3 - m);
    denom += (p0 + p1) + (p2 + p3);
    acc += p0 * x0; acc += p1 * x1; acc += p2 * x2; acc += p3 * x3;
  }
  for (; e < r1; ++e) {
    int s = clampN(col[e], N);
    float ev = ain + aj[s * 4 + h];
    ev = (ev > 0.f) ? ev : 0.2f * ev;
    float p = __expf(ev - m);
    denom += p;
    acc += p * xw[s * 4 + h];
  }
  float o = acc / denom;
  o += __shfl_xor(o, 1, 4);
  o += __shfl_xor(o, 2, 4);
  o *= 0.25f;
  if (h == 0) out[n] = o + b3[0];
}

extern "C" void kernel_launch(void* const* d_in, const int* in_sizes, int n_in,
                              void* d_out, int out_size, void* d_ws, size_t ws_size,
                              hipStream_t stream) {
  const float* X    = (const float*)d_in[0];
  const int*   ei   = (const int*)d_in[1];
  const float* W1   = (const float*)d_in[2];
  const float* att1 = (const float*)d_in[3];
  const float* b1   = (const float*)d_in[4];
  const float* W2   = (const float*)d_in[5];
  const float* att2 = (const float*)d_in[6];
  const float* b2   = (const float*)d_in[7];
  const float* W3   = (const float*)d_in[8];
  const float* att3 = (const float*)d_in[9];
  const float* b3   = (const float*)d_in[10];
  float* out = (float*)d_out;

  const int N  = in_sizes[0] / FDIM;   // 50000
  const int E  = in_sizes[1] / 2;      // 800000
  const int ET = E + N;
  const int NB = (N + BNODES - 1) >> BSHIFT;  // 391 buckets (<=512)

  char* ws = (char*)d_ws;
  auto carve = [&](size_t bytes) {
    char* p = ws; ws += (bytes + 15) & ~(size_t)15; return p;
  };
  float*    xw        = (float*)carve((size_t)N * 64 * 4);
  float*    hfeat     = (float*)carve((size_t)N * 64 * 4);
  float*    ai        = (float*)carve((size_t)N * 8 * 4);
  float*    aj        = (float*)carve((size_t)N * 8 * 4);
  int*      rowstart  = (int*)carve((size_t)(N + 1) * 4);
  int*      colidx    = (int*)carve((size_t)ET * 4);
  int*      stflag    = (int*)carve(16);
  unsigned* maxslot   = (unsigned*)carve(16);
  int*      bucketCnt = (int*)carve(512 * 4);
  int*      bucketBas = (int*)carve(513 * 4);
  int*      bucketFil = (int*)carve(512 * 4);
  size_t need = (size_t)(ws - (char*)d_ws);
  if (ws_size < need) return;
  int2* pairbuf = (int2*)xw;  // alias: CSR build precedes first GEMM write (needs ET*8 <= N*256)

  // ---- CSR build: bucketed counting sort (once; shared by all 3 layers) ----
  init_kernel<<<(NB + 255) / 256 + 1, 256, 0, stream>>>(ei, E, bucketCnt, NB, maxslot, stflag);
  hist_kernel<<<128, 256, 0, stream>>>(ei, stflag, E, N, NB, bucketCnt);
  bucket_scan_kernel<<<1, 512, 0, stream>>>(bucketCnt, NB, bucketBas, bucketFil,
                                            rowstart, N, ET);
  binscatter_kernel<<<(ET + BINCH - 1) / BINCH, 256, 0, stream>>>(
      ei, stflag, E, N, NB, bucketFil, pairbuf, ET);
  bucketbuild_kernel<<<NB, 256, 0, stream>>>(pairbuf, bucketBas, N, ET,
                                             rowstart, colidx);

  const int nodeBlocks4 = (N + 3) / 4;
  const int laneBlocks4 = (N * 4 + 255) / 256;

  // ---- layer 1 ----
  gemm_att64_kernel<<<1024, 256, 0, stream>>>(X, W1, att1, N, xw, ai, aj, maxslot + 0);
  gather64_kernel<<<nodeBlocks4, 256, 0, stream>>>(xw, ai, aj, rowstart, colidx,
                                                   b1, N, 1, hfeat, maxslot + 0);
  // ---- layer 2 ----
  gemm_att64_kernel<<<1024, 256, 0, stream>>>(hfeat, W2, att2, N, xw, ai, aj, maxslot + 1);
  gather64_kernel<<<nodeBlocks4, 256, 0, stream>>>(xw, ai, aj, rowstart, colidx,
                                                   b2, N, 1, hfeat, maxslot + 1);
  // ---- layer 3 ----
  gemm_att4_kernel<<<laneBlocks4, 256, 0, stream>>>(hfeat, W3, att3, N, xw, ai, aj, maxslot + 2);
  gather4_kernel<<<laneBlocks4, 256, 0, stream>>>(xw, ai, aj, rowstart, colidx,
                                                  b3, N, out, maxslot + 2);
}

// Round 7
// 276.581 us; speedup vs baseline: 2.3222x; 1.1219x over previous
//
#include <hip/hip_runtime.h>
#include <hip/hip_bf16.h>
#include <float.h>

// GAT, 3 layers: (8,8,concat) -> relu -> (8,8,concat) -> relu -> (4,1,mean)
// N=50000, E=800000 (+N self-loops).
// R6 -> R7:
//  * gather64: wave = 4 edge-slots x 16 lanes, float4 per lane. One dwordx4
//    wave-instr moves 4 edges' rows (was 1), one exp covers 4 edges. Slot
//    reduction via shfl_xor(16/32); slot-0 writes coalesced float4. x2 unroll.
//    (R6 counters: VALUBusy 64%, HBM 33% -> issue-bound, ~20 wave-instr/edge.)
//  * gemm_att64: 64-node tile, 4x4 register blocking, x staged transposed
//    (stride-68 pad: 16B-aligned, conflict-free b128 reads). LDS bytes/element
//    512 -> 128. Scores via per-jq partials + pair shfl (jq^1 shares head).
// CSR build (bucketed counting sort) unchanged from R6.

#define FDIM 64
#define BSHIFT 7                 // 128 nodes per bucket
#define BNODES (1 << BSHIFT)
#define BINCH 8192               // edges per binscatter block

__device__ __forceinline__ int clampN(int v, int N) {
  return ((unsigned)v >= (unsigned)N) ? 0 : v;
}
__device__ __forceinline__ unsigned f2ord(float f) {
  unsigned u = __float_as_uint(f);
  return (u & 0x80000000u) ? ~u : (u | 0x80000000u);
}
__device__ __forceinline__ float ord2f(unsigned o) {
  return __uint_as_float((o & 0x80000000u) ? (o & 0x7FFFFFFFu) : ~o);
}

// zero bucketCount + maxslots; block 0 detects edge_index word stride
// (int64 upload => odd 32-bit words all zero since ids < 2^31).
__global__ __launch_bounds__(256) void init_kernel(
    const int* __restrict__ ei, int E, int* __restrict__ bucketCount, int NB,
    unsigned* __restrict__ maxslot, int* __restrict__ flag) {
  int i = blockIdx.x * 256 + threadIdx.x;
  if (i < NB) bucketCount[i] = 0;
  if (i < 4) maxslot[i] = 0u;
  if (blockIdx.x == 0) {
    __shared__ int any;
    if (threadIdx.x == 0) any = 0;
    __syncthreads();
    int idx = 2 * threadIdx.x + 1;
    int v = (idx < 2 * E) ? ei[idx] : 0;
    if (v != 0) atomicOr(&any, 1);
    __syncthreads();
    if (threadIdx.x == 0) *flag = any ? 1 : 2;
  }
}

// coarse histogram of dst buckets (LDS-accumulated, few global atomics)
__global__ __launch_bounds__(256) void hist_kernel(
    const int* __restrict__ ei, const int* __restrict__ flag, int E, int N,
    int NB, int* __restrict__ bucketCount) {
  __shared__ int hist[512];
  int st = *flag;
  for (int i = threadIdx.x; i < NB; i += 256) hist[i] = 0;
  __syncthreads();
  int ET = E + N;
  for (int e = blockIdx.x * 256 + threadIdx.x; e < ET; e += gridDim.x * 256) {
    int dst = (e < E) ? clampN(ei[(size_t)st * (E + e)], N) : (e - E);
    atomicAdd(&hist[dst >> BSHIFT], 1);
  }
  __syncthreads();
  for (int i = threadIdx.x; i < NB; i += 256)
    if (hist[i]) atomicAdd(&bucketCount[i], hist[i]);
}

// 1-block scan of NB (<=512) bucket counts -> bucketBase (excl), fill=base
__global__ __launch_bounds__(512) void bucket_scan_kernel(
    const int* __restrict__ bucketCount, int NB, int* __restrict__ bucketBase,
    int* __restrict__ bucketFill, int* __restrict__ rowstart, int N, int ET) {
  __shared__ int s[512];
  int t = threadIdx.x;
  int v = (t < NB) ? bucketCount[t] : 0;
  s[t] = v;
  __syncthreads();
  for (int off = 1; off < 512; off <<= 1) {
    int x = (t >= off) ? s[t - off] : 0;
    __syncthreads();
    s[t] += x;
    __syncthreads();
  }
  if (t < NB) {
    int excl = s[t] - v;
    bucketBase[t] = excl;
    bucketFill[t] = excl;
  }
  if (t == 0) {
    bucketBase[NB] = s[511];  // == ET
    rowstart[N] = ET;
  }
}

// each block owns BINCH contiguous edges: LDS hist -> per-bucket global
// reservation -> write (src,dst) pairs into contiguous per-bucket streams
__global__ __launch_bounds__(256) void binscatter_kernel(
    const int* __restrict__ ei, const int* __restrict__ flag, int E, int N,
    int NB, int* __restrict__ bucketFill, int2* __restrict__ pairbuf, int ET) {
  __shared__ int hist[512];
  __shared__ int cursor[512];
  int st = *flag;
  int e0 = blockIdx.x * BINCH;
  int e1 = min(e0 + BINCH, ET);
  for (int i = threadIdx.x; i < NB; i += 256) hist[i] = 0;
  __syncthreads();
  for (int e = e0 + threadIdx.x; e < e1; e += 256) {
    int dst = (e < E) ? clampN(ei[(size_t)st * (E + e)], N) : (e - E);
    atomicAdd(&hist[dst >> BSHIFT], 1);
  }
  __syncthreads();
  for (int i = threadIdx.x; i < NB; i += 256)
    cursor[i] = hist[i] ? atomicAdd(&bucketFill[i], hist[i]) : 0;
  __syncthreads();
  for (int e = e0 + threadIdx.x; e < e1; e += 256) {
    int src, dst;
    if (e < E) {
      src = clampN(ei[(size_t)st * e], N);
      dst = clampN(ei[(size_t)st * (E + e)], N);
    } else {
      src = e - E; dst = e - E;
    }
    int pos = atomicAdd(&cursor[dst >> BSHIFT], 1);
    if ((unsigned)pos < (unsigned)ET) pairbuf[pos] = make_int2(src, dst);
  }
}

// one block per bucket: local degree count -> LDS scan -> rowstart; then
// cursor-scatter col within the bucket's contiguous edge range (L2-local)
__global__ __launch_bounds__(256) void bucketbuild_kernel(
    const int2* __restrict__ pairbuf, const int* __restrict__ bucketBase,
    int N, int ET, int* __restrict__ rowstart, int* __restrict__ col) {
  __shared__ int s[BNODES];
  int b = blockIdx.x;
  int t = threadIdx.x;
  int base = bucketBase[b], end = bucketBase[b + 1];
  int n0 = b << BSHIFT;
  int nn = min(BNODES, N - n0);
  if (t < BNODES) s[t] = 0;
  __syncthreads();
  for (int e = base + t; e < end; e += 256) {
    int li = pairbuf[e].y - n0;
    li = (li < 0) ? 0 : (li > BNODES - 1 ? BNODES - 1 : li);
    atomicAdd(&s[li], 1);
  }
  __syncthreads();
  int myd = (t < BNODES) ? s[t] : 0;
  for (int off = 1; off < BNODES; off <<= 1) {
    int v = (t >= off && t < BNODES) ? s[t - off] : 0;
    __syncthreads();
    if (t < BNODES) s[t] += v;
    __syncthreads();
  }
  int excl = (t < BNODES) ? (s[t] - myd) : 0;
  if (t < nn) rowstart[n0 + t] = base + excl;
  __syncthreads();
  if (t < BNODES) s[t] = excl;  // cursors
  __syncthreads();
  for (int e = base + t; e < end; e += 256) {
    int2 p = pairbuf[e];
    int li = p.y - n0;
    li = (li < 0) ? 0 : (li > BNODES - 1 ? BNODES - 1 : li);
    int pos = base + atomicAdd(&s[li], 1);
    if ((unsigned)pos < (unsigned)ET) col[pos] = p.x;
  }
}

// Layers 1-2 projection: xw = x@W (64x64) + per-node scores + global aj max.
// Block = 256 threads; tile = 64 nodes. Thread (nq=t>>4, jq=t&15) computes a
// 4x4 output block via 2 ds_read_b128 per k. xqT padded to stride 68
// (16B-aligned rows, conflict-free reads).
__global__ __launch_bounds__(256) void gemm_att64_kernel(
    const float* __restrict__ x, const float* __restrict__ W,
    const float* __restrict__ att, int N, float* __restrict__ xw,
    float* __restrict__ ai, float* __restrict__ aj,
    unsigned* __restrict__ maxslot) {
  __shared__ float Wl[64 * 64];
  __shared__ float xqT[64 * 68];  // [k][n], stride 68: 272B rows (16B aligned)
  __shared__ float red[4];
  int tid = threadIdx.x;
  for (int i = tid; i < 64 * 64; i += 256) Wl[i] = W[i];
  int jq = tid & 15, nq = tid >> 4;
  float aI[4], aJ[4];
  #pragma unroll
  for (int ji = 0; ji < 4; ++ji) {
    int j = jq * 4 + ji, h = j >> 3, c = j & 7;
    aI[ji] = att[h * 16 + c];
    aJ[ji] = att[h * 16 + 8 + c];
  }
  float pmax = -FLT_MAX;
  int ntiles = (N + 63) >> 6;
  for (int tile = blockIdx.x; tile < ntiles; tile += gridDim.x) {
    int n0 = tile << 6;
    __syncthreads();  // protect xqT reuse
    for (int idx = tid; idx < 4096; idx += 256) {
      int n = idx >> 6, k = idx & 63;   // per wave: k = lane (coalesced global)
      int gn = n0 + n;
      xqT[k * 68 + n] = (gn < N) ? x[(size_t)gn * 64 + k] : 0.f;
    }
    __syncthreads();
    float acc[4][4];
    #pragma unroll
    for (int i = 0; i < 4; ++i)
      #pragma unroll
      for (int j = 0; j < 4; ++j) acc[i][j] = 0.f;
    #pragma unroll 8
    for (int k = 0; k < 64; ++k) {
      float4 xv = *(const float4*)&xqT[k * 68 + nq * 4];
      float4 wv = *(const float4*)&Wl[k * 64 + jq * 4];
      acc[0][0] += xv.x * wv.x; acc[0][1] += xv.x * wv.y;
      acc[0][2] += xv.x * wv.z; acc[0][3] += xv.x * wv.w;
      acc[1][0] += xv.y * wv.x; acc[1][1] += xv.y * wv.y;
      acc[1][2] += xv.y * wv.z; acc[1][3] += xv.y * wv.w;
      acc[2][0] += xv.z * wv.x; acc[2][1] += xv.z * wv.y;
      acc[2][2] += xv.z * wv.z; acc[2][3] += xv.z * wv.w;
      acc[3][0] += xv.w * wv.x; acc[3][1] += xv.w * wv.y;
      acc[3][2] += xv.w * wv.z; acc[3][3] += xv.w * wv.w;
    }
    #pragma unroll
    for (int ni = 0; ni < 4; ++ni) {
      int gn = n0 + nq * 4 + ni;
      float pi = acc[ni][0] * aI[0] + acc[ni][1] * aI[1] +
                 acc[ni][2] * aI[2] + acc[ni][3] * aI[3];
      float pj = acc[ni][0] * aJ[0] + acc[ni][1] * aJ[1] +
                 acc[ni][2] * aJ[2] + acc[ni][3] * aJ[3];
      // jq and jq^1 cover the same head (j=4jq..4jq+3 => h=jq>>1)
      pi += __shfl_xor(pi, 1, 16);
      pj += __shfl_xor(pj, 1, 16);
      if (gn < N) {
        *(float4*)&xw[(size_t)gn * 64 + jq * 4] =
            make_float4(acc[ni][0], acc[ni][1], acc[ni][2], acc[ni][3]);
        if (!(jq & 1)) {
          int h = jq >> 1;
          ai[gn * 8 + h] = pi;
          aj[gn * 8 + h] = pj;
        }
        pmax = fmaxf(pmax, pj);
      }
    }
  }
  #pragma unroll
  for (int off = 1; off < 64; off <<= 1)
    pmax = fmaxf(pmax, __shfl_xor(pmax, off, 64));
  __syncthreads();
  if ((tid & 63) == 0) red[tid >> 6] = pmax;
  __syncthreads();
  if (tid == 0) {
    float m = fmaxf(fmaxf(red[0], red[1]), fmaxf(red[2], red[3]));
    atomicMax(maxslot, f2ord(m));
  }
}

// Layer 3 projection: xw = x@W3 (64x4), H=4, C=1, + global aj max.
__global__ __launch_bounds__(256) void gemm_att4_kernel(
    const float* __restrict__ x, const float* __restrict__ W,
    const float* __restrict__ att, int N, float* __restrict__ xw,
    float* __restrict__ ai, float* __restrict__ aj,
    unsigned* __restrict__ maxslot) {
  __shared__ float red[4];
  int t = blockIdx.x * 256 + threadIdx.x;
  int n = t >> 2;
  int j = t & 3;
  float pj = -FLT_MAX;
  if (n < N) {
    const float* xr = x + (size_t)n * 64;
    float acc = 0.f;
    #pragma unroll
    for (int k = 0; k < 64; ++k) acc += xr[k] * W[k * 4 + j];
    xw[n * 4 + j] = acc;
    ai[n * 4 + j] = acc * att[j * 2];
    pj = acc * att[j * 2 + 1];
    aj[n * 4 + j] = pj;
  }
  float pmax = pj;
  #pragma unroll
  for (int off = 1; off < 64; off <<= 1)
    pmax = fmaxf(pmax, __shfl_xor(pmax, off, 64));
  if ((threadIdx.x & 63) == 0) red[threadIdx.x >> 6] = pmax;
  __syncthreads();
  if (threadIdx.x == 0) {
    float m = fmaxf(fmaxf(red[0], red[1]), fmaxf(red[2], red[3]));
    atomicMax(maxslot, f2ord(m));
  }
}

// Layers 1-2 aggregation: block = 4 nodes (1 wave each).
// Wave = 4 edge-slots x 16 lanes; lane holds float4 of features f=4*li..4*li+3.
// One dwordx4 wave-instr moves 4 edges' rows; exp covers 4 edges per issue.
__global__ __launch_bounds__(256) void gather64_kernel(
    const float* __restrict__ xw, const float* __restrict__ ai,
    const float* __restrict__ aj, const int* __restrict__ rowstart,
    const int* __restrict__ col, const float* __restrict__ bias, int N,
    int relu, float* __restrict__ out, const unsigned* __restrict__ maxslot) {
  int n = blockIdx.x * 4 + (threadIdx.x >> 6);
  if (n >= N) return;
  float M = ord2f(*maxslot);
  int lane = threadIdx.x & 63;
  int slot = lane >> 4;   // which edge in the 4-group
  int li = lane & 15;     // feature quad
  int f4 = li * 4;
  int h = li >> 1;
  int r0 = rowstart[n], r1 = rowstart[n + 1];
  float ain = ai[n * 8 + h];
  float m = ain + M;               // >= local max (M >= all aj)
  m = (m > 0.f) ? m : 0.2f * m;    // leaky monotone => m >= local emax
  float dn = 0.f;
  float4 acc = make_float4(0.f, 0.f, 0.f, 0.f);
  int e = r0 + slot;
  for (; e + 4 < r1; e += 8) {     // 2 edges per slot in flight
    int sA = clampN(col[e], N);
    int sB = clampN(col[e + 4], N);
    float aA = aj[sA * 8 + h];
    float aB = aj[sB * 8 + h];
    float4 xA = *(const float4*)&xw[(size_t)sA * 64 + f4];
    float4 xB = *(const float4*)&xw[(size_t)sB * 64 + f4];
    float eA = ain + aA; eA = (eA > 0.f) ? eA : 0.2f * eA;
    float eB = ain + aB; eB = (eB > 0.f) ? eB : 0.2f * eB;
    float pA = __expf(eA - m);
    float pB = __expf(eB - m);
    dn += pA + pB;
    acc.x += pA * xA.x + pB * xB.x;
    acc.y += pA * xA.y + pB * xB.y;
    acc.z += pA * xA.z + pB * xB.z;
    acc.w += pA * xA.w + pB * xB.w;
  }
  if (e < r1) {
    int s = clampN(col[e], N);
    float a = aj[s * 8 + h];
    float4 xv = *(const float4*)&xw[(size_t)s * 64 + f4];
    float ev = ain + a; ev = (ev > 0.f) ? ev : 0.2f * ev;
    float p = __expf(ev - m);
    dn += p;
    acc.x += p * xv.x; acc.y += p * xv.y;
    acc.z += p * xv.z; acc.w += p * xv.w;
  }
  // reduce the 4 slots (lane bits 4 and 5)
  dn += __shfl_xor(dn, 16); dn += __shfl_xor(dn, 32);
  acc.x += __shfl_xor(acc.x, 16); acc.x += __shfl_xor(acc.x, 32);
  acc.y += __shfl_xor(acc.y, 16); acc.y += __shfl_xor(acc.y, 32);
  acc.z += __shfl_xor(acc.z, 16); acc.z += __shfl_xor(acc.z, 32);
  acc.w += __shfl_xor(acc.w, 16); acc.w += __shfl_xor(acc.w, 32);
  if (slot == 0) {
    float4 bv = *(const float4*)&bias[f4];
    float inv = 1.f / dn;
    float4 o = make_float4(acc.x * inv + bv.x, acc.y * inv + bv.y,
                           acc.z * inv + bv.z, acc.w * inv + bv.w);
    if (relu) {
      o.x = fmaxf(o.x, 0.f); o.y = fmaxf(o.y, 0.f);
      o.z = fmaxf(o.z, 0.f); o.w = fmaxf(o.w, 0.f);
    }
    *(float4*)&out[(size_t)n * 64 + f4] = o;
  }
}

// Layer 3 aggregation + head-mean + bias, single pass, unrolled x4.
__global__ __launch_bounds__(256) void gather4_kernel(
    const float* __restrict__ xw, const float* __restrict__ ai,
    const float* __restrict__ aj, const int* __restrict__ rowstart,
    const int* __restrict__ col, const float* __restrict__ b3, int N,
    float* __restrict__ out, const unsigned* __restrict__ maxslot) {
  int t = blockIdx.x * 256 + threadIdx.x;
  int n = t >> 2;
  if (n >= N) return;
  float M = ord2f(*maxslot);
  int h = t & 3;
  int r0 = rowstart[n], r1 = rowstart[n + 1];
  float ain = ai[n * 4 + h];
  float m = ain + M;
  m = (m > 0.f) ? m : 0.2f * m;
  float denom = 0.f, acc = 0.f;
  int e = r0;
  for (; e + 4 <= r1; e += 4) {
    int s0 = clampN(col[e + 0], N);
    int s1 = clampN(col[e + 1], N);
    int s2 = clampN(col[e + 2], N);
    int s3 = clampN(col[e + 3], N);
    float a0 = aj[s0 * 4 + h], a1 = aj[s1 * 4 + h];
    float a2 = aj[s2 * 4 + h], a3 = aj[s3 * 4 + h];
    float x0 = xw[s0 * 4 + h], x1 = xw[s1 * 4 + h];
    float x2 = xw[s2 * 4 + h], x3 = xw[s3 * 4 + h];
    float e0 = ain + a0; e0 = (e0 > 0.f) ? e0 : 0.2f * e0;
    float e1 = ain + a1; e1 = (e1 > 0.f) ? e1 : 0.2f * e1;
    float e2 = ain + a2; e2 = (e2 > 0.f) ? e2 : 0.2f * e2;
    float e3 = ain + a3; e3 = (e3 > 0.f) ? e3 : 0.2f * e3;
    float p0 = __expf(e0 - m), p1 = __expf(e1 - m);
    float p2 = __expf(e2 - m), p3 = __expf(e3 - m);
    denom += (p0 + p1) + (p2 + p3);
    acc += p0 * x0; acc += p1 * x1; acc += p2 * x2; acc += p3 * x3;
  }
  for (; e < r1; ++e) {
    int s = clampN(col[e], N);
    float ev = ain + aj[s * 4 + h];
    ev = (ev > 0.f) ? ev : 0.2f * ev;
    float p = __expf(ev - m);
    denom += p;
    acc += p * xw[s * 4 + h];
  }
  float o = acc / denom;
  o += __shfl_xor(o, 1, 4);
  o += __shfl_xor(o, 2, 4);
  o *= 0.25f;
  if (h == 0) out[n] = o + b3[0];
}

extern "C" void kernel_launch(void* const* d_in, const int* in_sizes, int n_in,
                              void* d_out, int out_size, void* d_ws, size_t ws_size,
                              hipStream_t stream) {
  const float* X    = (const float*)d_in[0];
  const int*   ei   = (const int*)d_in[1];
  const float* W1   = (const float*)d_in[2];
  const float* att1 = (const float*)d_in[3];
  const float* b1   = (const float*)d_in[4];
  const float* W2   = (const float*)d_in[5];
  const float* att2 = (const float*)d_in[6];
  const float* b2   = (const float*)d_in[7];
  const float* W3   = (const float*)d_in[8];
  const float* att3 = (const float*)d_in[9];
  const float* b3   = (const float*)d_in[10];
  float* out = (float*)d_out;

  const int N  = in_sizes[0] / FDIM;   // 50000
  const int E  = in_sizes[1] / 2;      // 800000
  const int ET = E + N;
  const int NB = (N + BNODES - 1) >> BSHIFT;  // 391 buckets (<=512)

  char* ws = (char*)d_ws;
  auto carve = [&](size_t bytes) {
    char* p = ws; ws += (bytes + 15) & ~(size_t)15; return p;
  };
  float*    xw        = (float*)carve((size_t)N * 64 * 4);
  float*    hfeat     = (float*)carve((size_t)N * 64 * 4);
  float*    ai        = (float*)carve((size_t)N * 8 * 4);
  float*    aj        = (float*)carve((size_t)N * 8 * 4);
  int*      rowstart  = (int*)carve((size_t)(N + 1) * 4);
  int*      colidx    = (int*)carve((size_t)ET * 4);
  int*      stflag    = (int*)carve(16);
  unsigned* maxslot   = (unsigned*)carve(16);
  int*      bucketCnt = (int*)carve(512 * 4);
  int*      bucketBas = (int*)carve(513 * 4);
  int*      bucketFil = (int*)carve(512 * 4);
  size_t need = (size_t)(ws - (char*)d_ws);
  if (ws_size < need) return;
  int2* pairbuf = (int2*)xw;  // alias: CSR build precedes first GEMM write

  // ---- CSR build: bucketed counting sort (once; shared by all 3 layers) ----
  init_kernel<<<(NB + 255) / 256 + 1, 256, 0, stream>>>(ei, E, bucketCnt, NB, maxslot, stflag);
  hist_kernel<<<128, 256, 0, stream>>>(ei, stflag, E, N, NB, bucketCnt);
  bucket_scan_kernel<<<1, 512, 0, stream>>>(bucketCnt, NB, bucketBas, bucketFil,
                                            rowstart, N, ET);
  binscatter_kernel<<<(ET + BINCH - 1) / BINCH, 256, 0, stream>>>(
      ei, stflag, E, N, NB, bucketFil, pairbuf, ET);
  bucketbuild_kernel<<<NB, 256, 0, stream>>>(pairbuf, bucketBas, N, ET,
                                             rowstart, colidx);

  const int nodeBlocks4 = (N + 3) / 4;
  const int laneBlocks4 = (N * 4 + 255) / 256;
  const int gemmTiles   = (N + 63) / 64;

  // ---- layer 1 ----
  gemm_att64_kernel<<<gemmTiles, 256, 0, stream>>>(X, W1, att1, N, xw, ai, aj, maxslot + 0);
  gather64_kernel<<<nodeBlocks4, 256, 0, stream>>>(xw, ai, aj, rowstart, colidx,
                                                   b1, N, 1, hfeat, maxslot + 0);
  // ---- layer 2 ----
  gemm_att64_kernel<<<gemmTiles, 256, 0, stream>>>(hfeat, W2, att2, N, xw, ai, aj, maxslot + 1);
  gather64_kernel<<<nodeBlocks4, 256, 0, stream>>>(xw, ai, aj, rowstart, colidx,
                                                   b2, N, 1, hfeat, maxslot + 1);
  // ---- layer 3 ----
  gemm_att4_kernel<<<laneBlocks4, 256, 0, stream>>>(hfeat, W3, att3, N, xw, ai, aj, maxslot + 2);
  gather4_kernel<<<laneBlocks4, 256, 0, stream>>>(xw, ai, aj, rowstart, colidx,
                                                  b3, N, out, maxslot + 2);
}

// Round 8
// 275.116 us; speedup vs baseline: 2.3346x; 1.0053x over previous
//
#include <hip/hip_runtime.h>
#include <hip/hip_bf16.h>
#include <float.h>

// GAT, 3 layers: (8,8,concat) -> relu -> (8,8,concat) -> relu -> (4,1,mean)
// N=50000, E=800000 (+N self-loops).
// R7 -> R8:
//  * gather64: 4 edges in flight per slot (was 2) -> 16 outstanding row loads
//    per wave. Diagnostic: helps iff the loop is miss-latency-bound (R7 ran at
//    ~2.7 TB/s L2-miss BW with only 2-deep MLP).
//  * pairbuf packed int2 -> uint (src<<7 | local_dst): halves the CSR
//    binscatter/bucketbuild streams.
// Everything else unchanged from R7.

#define FDIM 64
#define BSHIFT 7                 // 128 nodes per bucket
#define BNODES (1 << BSHIFT)
#define BINCH 8192               // edges per binscatter block

__device__ __forceinline__ int clampN(int v, int N) {
  return ((unsigned)v >= (unsigned)N) ? 0 : v;
}
__device__ __forceinline__ unsigned f2ord(float f) {
  unsigned u = __float_as_uint(f);
  return (u & 0x80000000u) ? ~u : (u | 0x80000000u);
}
__device__ __forceinline__ float ord2f(unsigned o) {
  return __uint_as_float((o & 0x80000000u) ? (o & 0x7FFFFFFFu) : ~o);
}

// zero bucketCount + maxslots; block 0 detects edge_index word stride
// (int64 upload => odd 32-bit words all zero since ids < 2^31).
__global__ __launch_bounds__(256) void init_kernel(
    const int* __restrict__ ei, int E, int* __restrict__ bucketCount, int NB,
    unsigned* __restrict__ maxslot, int* __restrict__ flag) {
  int i = blockIdx.x * 256 + threadIdx.x;
  if (i < NB) bucketCount[i] = 0;
  if (i < 4) maxslot[i] = 0u;
  if (blockIdx.x == 0) {
    __shared__ int any;
    if (threadIdx.x == 0) any = 0;
    __syncthreads();
    int idx = 2 * threadIdx.x + 1;
    int v = (idx < 2 * E) ? ei[idx] : 0;
    if (v != 0) atomicOr(&any, 1);
    __syncthreads();
    if (threadIdx.x == 0) *flag = any ? 1 : 2;
  }
}

// coarse histogram of dst buckets (LDS-accumulated, few global atomics)
__global__ __launch_bounds__(256) void hist_kernel(
    const int* __restrict__ ei, const int* __restrict__ flag, int E, int N,
    int NB, int* __restrict__ bucketCount) {
  __shared__ int hist[512];
  int st = *flag;
  for (int i = threadIdx.x; i < NB; i += 256) hist[i] = 0;
  __syncthreads();
  int ET = E + N;
  for (int e = blockIdx.x * 256 + threadIdx.x; e < ET; e += gridDim.x * 256) {
    int dst = (e < E) ? clampN(ei[(size_t)st * (E + e)], N) : (e - E);
    atomicAdd(&hist[dst >> BSHIFT], 1);
  }
  __syncthreads();
  for (int i = threadIdx.x; i < NB; i += 256)
    if (hist[i]) atomicAdd(&bucketCount[i], hist[i]);
}

// 1-block scan of NB (<=512) bucket counts -> bucketBase (excl), fill=base
__global__ __launch_bounds__(512) void bucket_scan_kernel(
    const int* __restrict__ bucketCount, int NB, int* __restrict__ bucketBase,
    int* __restrict__ bucketFill, int* __restrict__ rowstart, int N, int ET) {
  __shared__ int s[512];
  int t = threadIdx.x;
  int v = (t < NB) ? bucketCount[t] : 0;
  s[t] = v;
  __syncthreads();
  for (int off = 1; off < 512; off <<= 1) {
    int x = (t >= off) ? s[t - off] : 0;
    __syncthreads();
    s[t] += x;
    __syncthreads();
  }
  if (t < NB) {
    int excl = s[t] - v;
    bucketBase[t] = excl;
    bucketFill[t] = excl;
  }
  if (t == 0) {
    bucketBase[NB] = s[511];  // == ET
    rowstart[N] = ET;
  }
}

// each block owns BINCH contiguous edges: LDS hist -> per-bucket global
// reservation -> write packed (src<<7|localdst) into per-bucket streams
__global__ __launch_bounds__(256) void binscatter_kernel(
    const int* __restrict__ ei, const int* __restrict__ flag, int E, int N,
    int NB, int* __restrict__ bucketFill, unsigned* __restrict__ pairbuf,
    int ET) {
  __shared__ int hist[512];
  __shared__ int cursor[512];
  int st = *flag;
  int e0 = blockIdx.x * BINCH;
  int e1 = min(e0 + BINCH, ET);
  for (int i = threadIdx.x; i < NB; i += 256) hist[i] = 0;
  __syncthreads();
  for (int e = e0 + threadIdx.x; e < e1; e += 256) {
    int dst = (e < E) ? clampN(ei[(size_t)st * (E + e)], N) : (e - E);
    atomicAdd(&hist[dst >> BSHIFT], 1);
  }
  __syncthreads();
  for (int i = threadIdx.x; i < NB; i += 256)
    cursor[i] = hist[i] ? atomicAdd(&bucketFill[i], hist[i]) : 0;
  __syncthreads();
  for (int e = e0 + threadIdx.x; e < e1; e += 256) {
    int src, dst;
    if (e < E) {
      src = clampN(ei[(size_t)st * e], N);
      dst = clampN(ei[(size_t)st * (E + e)], N);
    } else {
      src = e - E; dst = e - E;
    }
    int pos = atomicAdd(&cursor[dst >> BSHIFT], 1);
    if ((unsigned)pos < (unsigned)ET)
      pairbuf[pos] = ((unsigned)src << BSHIFT) | (unsigned)(dst & (BNODES - 1));
  }
}

// one block per bucket: local degree count -> LDS scan -> rowstart; then
// cursor-scatter col within the bucket's contiguous edge range (L2-local)
__global__ __launch_bounds__(256) void bucketbuild_kernel(
    const unsigned* __restrict__ pairbuf, const int* __restrict__ bucketBase,
    int N, int ET, int* __restrict__ rowstart, int* __restrict__ col) {
  __shared__ int s[BNODES];
  int b = blockIdx.x;
  int t = threadIdx.x;
  int base = bucketBase[b], end = bucketBase[b + 1];
  int n0 = b << BSHIFT;
  int nn = min(BNODES, N - n0);
  if (t < BNODES) s[t] = 0;
  __syncthreads();
  for (int e = base + t; e < end; e += 256) {
    int li = pairbuf[e] & (BNODES - 1);
    atomicAdd(&s[li], 1);
  }
  __syncthreads();
  int myd = (t < BNODES) ? s[t] : 0;
  for (int off = 1; off < BNODES; off <<= 1) {
    int v = (t >= off && t < BNODES) ? s[t - off] : 0;
    __syncthreads();
    if (t < BNODES) s[t] += v;
    __syncthreads();
  }
  int excl = (t < BNODES) ? (s[t] - myd) : 0;
  if (t < nn) rowstart[n0 + t] = base + excl;
  __syncthreads();
  if (t < BNODES) s[t] = excl;  // cursors
  __syncthreads();
  for (int e = base + t; e < end; e += 256) {
    unsigned p = pairbuf[e];
    int li = p & (BNODES - 1);
    int pos = base + atomicAdd(&s[li], 1);
    if ((unsigned)pos < (unsigned)ET) col[pos] = (int)(p >> BSHIFT);
  }
}

// Layers 1-2 projection: xw = x@W (64x64) + per-node scores + global aj max.
// Block = 256 threads; tile = 64 nodes; thread computes a 4x4 output block.
__global__ __launch_bounds__(256) void gemm_att64_kernel(
    const float* __restrict__ x, const float* __restrict__ W,
    const float* __restrict__ att, int N, float* __restrict__ xw,
    float* __restrict__ ai, float* __restrict__ aj,
    unsigned* __restrict__ maxslot) {
  __shared__ float Wl[64 * 64];
  __shared__ float xqT[64 * 68];  // [k][n], stride 68: 272B rows (16B aligned)
  __shared__ float red[4];
  int tid = threadIdx.x;
  for (int i = tid; i < 64 * 64; i += 256) Wl[i] = W[i];
  int jq = tid & 15, nq = tid >> 4;
  float aI[4], aJ[4];
  #pragma unroll
  for (int ji = 0; ji < 4; ++ji) {
    int j = jq * 4 + ji, h = j >> 3, c = j & 7;
    aI[ji] = att[h * 16 + c];
    aJ[ji] = att[h * 16 + 8 + c];
  }
  float pmax = -FLT_MAX;
  int ntiles = (N + 63) >> 6;
  for (int tile = blockIdx.x; tile < ntiles; tile += gridDim.x) {
    int n0 = tile << 6;
    __syncthreads();  // protect xqT reuse
    for (int idx = tid; idx < 4096; idx += 256) {
      int n = idx >> 6, k = idx & 63;   // per wave: k = lane (coalesced)
      int gn = n0 + n;
      xqT[k * 68 + n] = (gn < N) ? x[(size_t)gn * 64 + k] : 0.f;
    }
    __syncthreads();
    float acc[4][4];
    #pragma unroll
    for (int i = 0; i < 4; ++i)
      #pragma unroll
      for (int j = 0; j < 4; ++j) acc[i][j] = 0.f;
    #pragma unroll 8
    for (int k = 0; k < 64; ++k) {
      float4 xv = *(const float4*)&xqT[k * 68 + nq * 4];
      float4 wv = *(const float4*)&Wl[k * 64 + jq * 4];
      acc[0][0] += xv.x * wv.x; acc[0][1] += xv.x * wv.y;
      acc[0][2] += xv.x * wv.z; acc[0][3] += xv.x * wv.w;
      acc[1][0] += xv.y * wv.x; acc[1][1] += xv.y * wv.y;
      acc[1][2] += xv.y * wv.z; acc[1][3] += xv.y * wv.w;
      acc[2][0] += xv.z * wv.x; acc[2][1] += xv.z * wv.y;
      acc[2][2] += xv.z * wv.z; acc[2][3] += xv.z * wv.w;
      acc[3][0] += xv.w * wv.x; acc[3][1] += xv.w * wv.y;
      acc[3][2] += xv.w * wv.z; acc[3][3] += xv.w * wv.w;
    }
    #pragma unroll
    for (int ni = 0; ni < 4; ++ni) {
      int gn = n0 + nq * 4 + ni;
      float pi = acc[ni][0] * aI[0] + acc[ni][1] * aI[1] +
                 acc[ni][2] * aI[2] + acc[ni][3] * aI[3];
      float pj = acc[ni][0] * aJ[0] + acc[ni][1] * aJ[1] +
                 acc[ni][2] * aJ[2] + acc[ni][3] * aJ[3];
      // jq and jq^1 cover the same head (j=4jq..4jq+3 => h=jq>>1)
      pi += __shfl_xor(pi, 1, 16);
      pj += __shfl_xor(pj, 1, 16);
      if (gn < N) {
        *(float4*)&xw[(size_t)gn * 64 + jq * 4] =
            make_float4(acc[ni][0], acc[ni][1], acc[ni][2], acc[ni][3]);
        if (!(jq & 1)) {
          int h = jq >> 1;
          ai[gn * 8 + h] = pi;
          aj[gn * 8 + h] = pj;
        }
        pmax = fmaxf(pmax, pj);
      }
    }
  }
  #pragma unroll
  for (int off = 1; off < 64; off <<= 1)
    pmax = fmaxf(pmax, __shfl_xor(pmax, off, 64));
  __syncthreads();
  if ((tid & 63) == 0) red[tid >> 6] = pmax;
  __syncthreads();
  if (tid == 0) {
    float m = fmaxf(fmaxf(red[0], red[1]), fmaxf(red[2], red[3]));
    atomicMax(maxslot, f2ord(m));
  }
}

// Layer 3 projection: xw = x@W3 (64x4), H=4, C=1, + global aj max.
__global__ __launch_bounds__(256) void gemm_att4_kernel(
    const float* __restrict__ x, const float* __restrict__ W,
    const float* __restrict__ att, int N, float* __restrict__ xw,
    float* __restrict__ ai, float* __restrict__ aj,
    unsigned* __restrict__ maxslot) {
  __shared__ float red[4];
  int t = blockIdx.x * 256 + threadIdx.x;
  int n = t >> 2;
  int j = t & 3;
  float pj = -FLT_MAX;
  if (n < N) {
    const float* xr = x + (size_t)n * 64;
    float acc = 0.f;
    #pragma unroll
    for (int k = 0; k < 64; ++k) acc += xr[k] * W[k * 4 + j];
    xw[n * 4 + j] = acc;
    ai[n * 4 + j] = acc * att[j * 2];
    pj = acc * att[j * 2 + 1];
    aj[n * 4 + j] = pj;
  }
  float pmax = pj;
  #pragma unroll
  for (int off = 1; off < 64; off <<= 1)
    pmax = fmaxf(pmax, __shfl_xor(pmax, off, 64));
  if ((threadIdx.x & 63) == 0) red[threadIdx.x >> 6] = pmax;
  __syncthreads();
  if (threadIdx.x == 0) {
    float m = fmaxf(fmaxf(red[0], red[1]), fmaxf(red[2], red[3]));
    atomicMax(maxslot, f2ord(m));
  }
}

// Layers 1-2 aggregation: block = 4 nodes (1 wave each).
// Wave = 4 edge-slots x 16 lanes; lane holds float4 of features f=4*li..4*li+3.
// 4 edges in flight per slot (16 outstanding row loads per wave).
__global__ __launch_bounds__(256) void gather64_kernel(
    const float* __restrict__ xw, const float* __restrict__ ai,
    const float* __restrict__ aj, const int* __restrict__ rowstart,
    const int* __restrict__ col, const float* __restrict__ bias, int N,
    int relu, float* __restrict__ out, const unsigned* __restrict__ maxslot) {
  int n = blockIdx.x * 4 + (threadIdx.x >> 6);
  if (n >= N) return;
  float M = ord2f(*maxslot);
  int lane = threadIdx.x & 63;
  int slot = lane >> 4;   // which edge in the 4-group
  int li = lane & 15;     // feature quad
  int f4 = li * 4;
  int h = li >> 1;
  int r0 = rowstart[n], r1 = rowstart[n + 1];
  float ain = ai[n * 8 + h];
  float m = ain + M;               // >= local max (M >= all aj)
  m = (m > 0.f) ? m : 0.2f * m;    // leaky monotone => m >= local emax
  float dn = 0.f;
  float4 acc = make_float4(0.f, 0.f, 0.f, 0.f);
  int e = r0 + slot;
  for (; e + 12 < r1; e += 16) {   // 4 edges per slot in flight
    int sA = clampN(col[e],      N);
    int sB = clampN(col[e + 4],  N);
    int sC = clampN(col[e + 8],  N);
    int sD = clampN(col[e + 12], N);
    float aA = aj[sA * 8 + h], aB = aj[sB * 8 + h];
    float aC = aj[sC * 8 + h], aD = aj[sD * 8 + h];
    float4 xA = *(const float4*)&xw[(size_t)sA * 64 + f4];
    float4 xB = *(const float4*)&xw[(size_t)sB * 64 + f4];
    float4 xC = *(const float4*)&xw[(size_t)sC * 64 + f4];
    float4 xD = *(const float4*)&xw[(size_t)sD * 64 + f4];
    float eA = ain + aA; eA = (eA > 0.f) ? eA : 0.2f * eA;
    float eB = ain + aB; eB = (eB > 0.f) ? eB : 0.2f * eB;
    float eC = ain + aC; eC = (eC > 0.f) ? eC : 0.2f * eC;
    float eD = ain + aD; eD = (eD > 0.f) ? eD : 0.2f * eD;
    float pA = __expf(eA - m), pB = __expf(eB - m);
    float pC = __expf(eC - m), pD = __expf(eD - m);
    dn += (pA + pB) + (pC + pD);
    acc.x += pA * xA.x + pB * xB.x + pC * xC.x + pD * xD.x;
    acc.y += pA * xA.y + pB * xB.y + pC * xC.y + pD * xD.y;
    acc.z += pA * xA.z + pB * xB.z + pC * xC.z + pD * xD.z;
    acc.w += pA * xA.w + pB * xB.w + pC * xC.w + pD * xD.w;
  }
  for (; e < r1; e += 4) {
    int s = clampN(col[e], N);
    float a = aj[s * 8 + h];
    float4 xv = *(const float4*)&xw[(size_t)s * 64 + f4];
    float ev = ain + a; ev = (ev > 0.f) ? ev : 0.2f * ev;
    float p = __expf(ev - m);
    dn += p;
    acc.x += p * xv.x; acc.y += p * xv.y;
    acc.z += p * xv.z; acc.w += p * xv.w;
  }
  // reduce the 4 slots (lane bits 4 and 5)
  dn += __shfl_xor(dn, 16); dn += __shfl_xor(dn, 32);
  acc.x += __shfl_xor(acc.x, 16); acc.x += __shfl_xor(acc.x, 32);
  acc.y += __shfl_xor(acc.y, 16); acc.y += __shfl_xor(acc.y, 32);
  acc.z += __shfl_xor(acc.z, 16); acc.z += __shfl_xor(acc.z, 32);
  acc.w += __shfl_xor(acc.w, 16); acc.w += __shfl_xor(acc.w, 32);
  if (slot == 0) {
    float4 bv = *(const float4*)&bias[f4];
    float inv = 1.f / dn;
    float4 o = make_float4(acc.x * inv + bv.x, acc.y * inv + bv.y,
                           acc.z * inv + bv.z, acc.w * inv + bv.w);
    if (relu) {
      o.x = fmaxf(o.x, 0.f); o.y = fmaxf(o.y, 0.f);
      o.z = fmaxf(o.z, 0.f); o.w = fmaxf(o.w, 0.f);
    }
    *(float4*)&out[(size_t)n * 64 + f4] = o;
  }
}

// Layer 3 aggregation + head-mean + bias, single pass, unrolled x4.
__global__ __launch_bounds__(256) void gather4_kernel(
    const float* __restrict__ xw, const float* __restrict__ ai,
    const float* __restrict__ aj, const int* __restrict__ rowstart,
    const int* __restrict__ col, const float* __restrict__ b3, int N,
    float* __restrict__ out, const unsigned* __restrict__ maxslot) {
  int t = blockIdx.x * 256 + threadIdx.x;
  int n = t >> 2;
  if (n >= N) return;
  float M = ord2f(*maxslot);
  int h = t & 3;
  int r0 = rowstart[n], r1 = rowstart[n + 1];
  float ain = ai[n * 4 + h];
  float m = ain + M;
  m = (m > 0.f) ? m : 0.2f * m;
  float denom = 0.f, acc = 0.f;
  int e = r0;
  for (; e + 4 <= r1; e += 4) {
    int s0 = clampN(col[e + 0], N);
    int s1 = clampN(col[e + 1], N);
    int s2 = clampN(col[e + 2], N);
    int s3 = clampN(col[e + 3], N);
    float a0 = aj[s0 * 4 + h], a1 = aj[s1 * 4 + h];
    float a2 = aj[s2 * 4 + h], a3 = aj[s3 * 4 + h];
    float x0 = xw[s0 * 4 + h], x1 = xw[s1 * 4 + h];
    float x2 = xw[s2 * 4 + h], x3 = xw[s3 * 4 + h];
    float e0 = ain + a0; e0 = (e0 > 0.f) ? e0 : 0.2f * e0;
    float e1 = ain + a1; e1 = (e1 > 0.f) ? e1 : 0.2f * e1;
    float e2 = ain + a2; e2 = (e2 > 0.f) ? e2 : 0.2f * e2;
    float e3 = ain + a3; e3 = (e3 > 0.f) ? e3 : 0.2f * e3;
    float p0 = __expf(e0 - m), p1 = __expf(e1 - m);
    float p2 = __expf(e2 - m), p3 = __expf(e3 - m);
    denom += (p0 + p1) + (p2 + p3);
    acc += p0 * x0; acc += p1 * x1; acc += p2 * x2; acc += p3 * x3;
  }
  for (; e < r1; ++e) {
    int s = clampN(col[e], N);
    float ev = ain + aj[s * 4 + h];
    ev = (ev > 0.f) ? ev : 0.2f * ev;
    float p = __expf(ev - m);
    denom += p;
    acc += p * xw[s * 4 + h];
  }
  float o = acc / denom;
  o += __shfl_xor(o, 1, 4);
  o += __shfl_xor(o, 2, 4);
  o *= 0.25f;
  if (h == 0) out[n] = o + b3[0];
}

extern "C" void kernel_launch(void* const* d_in, const int* in_sizes, int n_in,
                              void* d_out, int out_size, void* d_ws, size_t ws_size,
                              hipStream_t stream) {
  const float* X    = (const float*)d_in[0];
  const int*   ei   = (const int*)d_in[1];
  const float* W1   = (const float*)d_in[2];
  const float* att1 = (const float*)d_in[3];
  const float* b1   = (const float*)d_in[4];
  const float* W2   = (const float*)d_in[5];
  const float* att2 = (const float*)d_in[6];
  const float* b2   = (const float*)d_in[7];
  const float* W3   = (const float*)d_in[8];
  const float* att3 = (const float*)d_in[9];
  const float* b3   = (const float*)d_in[10];
  float* out = (float*)d_out;

  const int N  = in_sizes[0] / FDIM;   // 50000
  const int E  = in_sizes[1] / 2;      // 800000
  const int ET = E + N;
  const int NB = (N + BNODES - 1) >> BSHIFT;  // 391 buckets (<=512)

  char* ws = (char*)d_ws;
  auto carve = [&](size_t bytes) {
    char* p = ws; ws += (bytes + 15) & ~(size_t)15; return p;
  };
  float*    xw        = (float*)carve((size_t)N * 64 * 4);
  float*    hfeat     = (float*)carve((size_t)N * 64 * 4);
  float*    ai        = (float*)carve((size_t)N * 8 * 4);
  float*    aj        = (float*)carve((size_t)N * 8 * 4);
  int*      rowstart  = (int*)carve((size_t)(N + 1) * 4);
  int*      colidx    = (int*)carve((size_t)ET * 4);
  int*      stflag    = (int*)carve(16);
  unsigned* maxslot   = (unsigned*)carve(16);
  int*      bucketCnt = (int*)carve(512 * 4);
  int*      bucketBas = (int*)carve(513 * 4);
  int*      bucketFil = (int*)carve(512 * 4);
  size_t need = (size_t)(ws - (char*)d_ws);
  if (ws_size < need) return;
  unsigned* pairbuf = (unsigned*)xw;  // alias: CSR build precedes first GEMM

  // ---- CSR build: bucketed counting sort (once; shared by all 3 layers) ----
  init_kernel<<<(NB + 255) / 256 + 1, 256, 0, stream>>>(ei, E, bucketCnt, NB, maxslot, stflag);
  hist_kernel<<<128, 256, 0, stream>>>(ei, stflag, E, N, NB, bucketCnt);
  bucket_scan_kernel<<<1, 512, 0, stream>>>(bucketCnt, NB, bucketBas, bucketFil,
                                            rowstart, N, ET);
  binscatter_kernel<<<(ET + BINCH - 1) / BINCH, 256, 0, stream>>>(
      ei, stflag, E, N, NB, bucketFil, pairbuf, ET);
  bucketbuild_kernel<<<NB, 256, 0, stream>>>(pairbuf, bucketBas, N, ET,
                                             rowstart, colidx);

  const int nodeBlocks4 = (N + 3) / 4;
  const int laneBlocks4 = (N * 4 + 255) / 256;
  const int gemmTiles   = (N + 63) / 64;

  // ---- layer 1 ----
  gemm_att64_kernel<<<gemmTiles, 256, 0, stream>>>(X, W1, att1, N, xw, ai, aj, maxslot + 0);
  gather64_kernel<<<nodeBlocks4, 256, 0, stream>>>(xw, ai, aj, rowstart, colidx,
                                                   b1, N, 1, hfeat, maxslot + 0);
  // ---- layer 2 ----
  gemm_att64_kernel<<<gemmTiles, 256, 0, stream>>>(hfeat, W2, att2, N, xw, ai, aj, maxslot + 1);
  gather64_kernel<<<nodeBlocks4, 256, 0, stream>>>(xw, ai, aj, rowstart, colidx,
                                                   b2, N, 1, hfeat, maxslot + 1);
  // ---- layer 3 ----
  gemm_att4_kernel<<<laneBlocks4, 256, 0, stream>>>(hfeat, W3, att3, N, xw, ai, aj, maxslot + 2);
  gather4_kernel<<<laneBlocks4, 256, 0, stream>>>(xw, ai, aj, rowstart, colidx,
                                                  b3, N, out, maxslot + 2);
}

// Round 9
// 259.488 us; speedup vs baseline: 2.4752x; 1.0602x over previous
//
#include <hip/hip_runtime.h>
#include <hip/hip_bf16.h>
#include <hip/hip_fp16.h>
#include <float.h>

// GAT, 3 layers: (8,8,concat) -> relu -> (8,8,concat) -> relu -> (4,1,mean)
// N=50000, E=800000 (+N self-loops).
// R8 -> R9: xw (layers 1-2 gather operand) stored as fp16 (half2-packed).
//   R8 null-result on 4-deep unroll => gather64 is random-fetch-BW-bound
//   (218MB logical, 109MB FETCH at ~2.6TB/s). fp16 halves logical bytes and
//   drops working set 12.8->6.4MB (better per-XCD L2 fit). Scores ai/aj stay
//   fp32 (computed pre-rounding); accumulation fp32; layer-3 xw3 stays fp32.
// CSR build (bucketed counting sort, packed pairbuf) unchanged from R8.

#define FDIM 64
#define BSHIFT 7                 // 128 nodes per bucket
#define BNODES (1 << BSHIFT)
#define BINCH 8192               // edges per binscatter block

__device__ __forceinline__ int clampN(int v, int N) {
  return ((unsigned)v >= (unsigned)N) ? 0 : v;
}
__device__ __forceinline__ unsigned f2ord(float f) {
  unsigned u = __float_as_uint(f);
  return (u & 0x80000000u) ? ~u : (u | 0x80000000u);
}
__device__ __forceinline__ float ord2f(unsigned o) {
  return __uint_as_float((o & 0x80000000u) ? (o & 0x7FFFFFFFu) : ~o);
}

// zero bucketCount + maxslots; block 0 detects edge_index word stride
// (int64 upload => odd 32-bit words all zero since ids < 2^31).
__global__ __launch_bounds__(256) void init_kernel(
    const int* __restrict__ ei, int E, int* __restrict__ bucketCount, int NB,
    unsigned* __restrict__ maxslot, int* __restrict__ flag) {
  int i = blockIdx.x * 256 + threadIdx.x;
  if (i < NB) bucketCount[i] = 0;
  if (i < 4) maxslot[i] = 0u;
  if (blockIdx.x == 0) {
    __shared__ int any;
    if (threadIdx.x == 0) any = 0;
    __syncthreads();
    int idx = 2 * threadIdx.x + 1;
    int v = (idx < 2 * E) ? ei[idx] : 0;
    if (v != 0) atomicOr(&any, 1);
    __syncthreads();
    if (threadIdx.x == 0) *flag = any ? 1 : 2;
  }
}

// coarse histogram of dst buckets (LDS-accumulated, few global atomics)
__global__ __launch_bounds__(256) void hist_kernel(
    const int* __restrict__ ei, const int* __restrict__ flag, int E, int N,
    int NB, int* __restrict__ bucketCount) {
  __shared__ int hist[512];
  int st = *flag;
  for (int i = threadIdx.x; i < NB; i += 256) hist[i] = 0;
  __syncthreads();
  int ET = E + N;
  for (int e = blockIdx.x * 256 + threadIdx.x; e < ET; e += gridDim.x * 256) {
    int dst = (e < E) ? clampN(ei[(size_t)st * (E + e)], N) : (e - E);
    atomicAdd(&hist[dst >> BSHIFT], 1);
  }
  __syncthreads();
  for (int i = threadIdx.x; i < NB; i += 256)
    if (hist[i]) atomicAdd(&bucketCount[i], hist[i]);
}

// 1-block scan of NB (<=512) bucket counts -> bucketBase (excl), fill=base
__global__ __launch_bounds__(512) void bucket_scan_kernel(
    const int* __restrict__ bucketCount, int NB, int* __restrict__ bucketBase,
    int* __restrict__ bucketFill, int* __restrict__ rowstart, int N, int ET) {
  __shared__ int s[512];
  int t = threadIdx.x;
  int v = (t < NB) ? bucketCount[t] : 0;
  s[t] = v;
  __syncthreads();
  for (int off = 1; off < 512; off <<= 1) {
    int x = (t >= off) ? s[t - off] : 0;
    __syncthreads();
    s[t] += x;
    __syncthreads();
  }
  if (t < NB) {
    int excl = s[t] - v;
    bucketBase[t] = excl;
    bucketFill[t] = excl;
  }
  if (t == 0) {
    bucketBase[NB] = s[511];  // == ET
    rowstart[N] = ET;
  }
}

// each block owns BINCH contiguous edges: LDS hist -> per-bucket global
// reservation -> write packed (src<<7|localdst) into per-bucket streams
__global__ __launch_bounds__(256) void binscatter_kernel(
    const int* __restrict__ ei, const int* __restrict__ flag, int E, int N,
    int NB, int* __restrict__ bucketFill, unsigned* __restrict__ pairbuf,
    int ET) {
  __shared__ int hist[512];
  __shared__ int cursor[512];
  int st = *flag;
  int e0 = blockIdx.x * BINCH;
  int e1 = min(e0 + BINCH, ET);
  for (int i = threadIdx.x; i < NB; i += 256) hist[i] = 0;
  __syncthreads();
  for (int e = e0 + threadIdx.x; e < e1; e += 256) {
    int dst = (e < E) ? clampN(ei[(size_t)st * (E + e)], N) : (e - E);
    atomicAdd(&hist[dst >> BSHIFT], 1);
  }
  __syncthreads();
  for (int i = threadIdx.x; i < NB; i += 256)
    cursor[i] = hist[i] ? atomicAdd(&bucketFill[i], hist[i]) : 0;
  __syncthreads();
  for (int e = e0 + threadIdx.x; e < e1; e += 256) {
    int src, dst;
    if (e < E) {
      src = clampN(ei[(size_t)st * e], N);
      dst = clampN(ei[(size_t)st * (E + e)], N);
    } else {
      src = e - E; dst = e - E;
    }
    int pos = atomicAdd(&cursor[dst >> BSHIFT], 1);
    if ((unsigned)pos < (unsigned)ET)
      pairbuf[pos] = ((unsigned)src << BSHIFT) | (unsigned)(dst & (BNODES - 1));
  }
}

// one block per bucket: local degree count -> LDS scan -> rowstart; then
// cursor-scatter col within the bucket's contiguous edge range (L2-local)
__global__ __launch_bounds__(256) void bucketbuild_kernel(
    const unsigned* __restrict__ pairbuf, const int* __restrict__ bucketBase,
    int N, int ET, int* __restrict__ rowstart, int* __restrict__ col) {
  __shared__ int s[BNODES];
  int b = blockIdx.x;
  int t = threadIdx.x;
  int base = bucketBase[b], end = bucketBase[b + 1];
  int n0 = b << BSHIFT;
  int nn = min(BNODES, N - n0);
  if (t < BNODES) s[t] = 0;
  __syncthreads();
  for (int e = base + t; e < end; e += 256) {
    int li = pairbuf[e] & (BNODES - 1);
    atomicAdd(&s[li], 1);
  }
  __syncthreads();
  int myd = (t < BNODES) ? s[t] : 0;
  for (int off = 1; off < BNODES; off <<= 1) {
    int v = (t >= off && t < BNODES) ? s[t - off] : 0;
    __syncthreads();
    if (t < BNODES) s[t] += v;
    __syncthreads();
  }
  int excl = (t < BNODES) ? (s[t] - myd) : 0;
  if (t < nn) rowstart[n0 + t] = base + excl;
  __syncthreads();
  if (t < BNODES) s[t] = excl;  // cursors
  __syncthreads();
  for (int e = base + t; e < end; e += 256) {
    unsigned p = pairbuf[e];
    int li = p & (BNODES - 1);
    int pos = base + atomicAdd(&s[li], 1);
    if ((unsigned)pos < (unsigned)ET) col[pos] = (int)(p >> BSHIFT);
  }
}

// Layers 1-2 projection: xwh(fp16) = x@W (64x64) + fp32 scores + global aj max.
// Block = 256 threads; tile = 64 nodes; thread computes a 4x4 output block.
__global__ __launch_bounds__(256) void gemm_att64_kernel(
    const float* __restrict__ x, const float* __restrict__ W,
    const float* __restrict__ att, int N, __half* __restrict__ xwh,
    float* __restrict__ ai, float* __restrict__ aj,
    unsigned* __restrict__ maxslot) {
  __shared__ float Wl[64 * 64];
  __shared__ float xqT[64 * 68];  // [k][n], stride 68: 272B rows (16B aligned)
  __shared__ float red[4];
  int tid = threadIdx.x;
  for (int i = tid; i < 64 * 64; i += 256) Wl[i] = W[i];
  int jq = tid & 15, nq = tid >> 4;
  float aI[4], aJ[4];
  #pragma unroll
  for (int ji = 0; ji < 4; ++ji) {
    int j = jq * 4 + ji, h = j >> 3, c = j & 7;
    aI[ji] = att[h * 16 + c];
    aJ[ji] = att[h * 16 + 8 + c];
  }
  float pmax = -FLT_MAX;
  int ntiles = (N + 63) >> 6;
  for (int tile = blockIdx.x; tile < ntiles; tile += gridDim.x) {
    int n0 = tile << 6;
    __syncthreads();  // protect xqT reuse
    for (int idx = tid; idx < 4096; idx += 256) {
      int n = idx >> 6, k = idx & 63;   // per wave: k = lane (coalesced)
      int gn = n0 + n;
      xqT[k * 68 + n] = (gn < N) ? x[(size_t)gn * 64 + k] : 0.f;
    }
    __syncthreads();
    float acc[4][4];
    #pragma unroll
    for (int i = 0; i < 4; ++i)
      #pragma unroll
      for (int j = 0; j < 4; ++j) acc[i][j] = 0.f;
    #pragma unroll 8
    for (int k = 0; k < 64; ++k) {
      float4 xv = *(const float4*)&xqT[k * 68 + nq * 4];
      float4 wv = *(const float4*)&Wl[k * 64 + jq * 4];
      acc[0][0] += xv.x * wv.x; acc[0][1] += xv.x * wv.y;
      acc[0][2] += xv.x * wv.z; acc[0][3] += xv.x * wv.w;
      acc[1][0] += xv.y * wv.x; acc[1][1] += xv.y * wv.y;
      acc[1][2] += xv.y * wv.z; acc[1][3] += xv.y * wv.w;
      acc[2][0] += xv.z * wv.x; acc[2][1] += xv.z * wv.y;
      acc[2][2] += xv.z * wv.z; acc[2][3] += xv.z * wv.w;
      acc[3][0] += xv.w * wv.x; acc[3][1] += xv.w * wv.y;
      acc[3][2] += xv.w * wv.z; acc[3][3] += xv.w * wv.w;
    }
    #pragma unroll
    for (int ni = 0; ni < 4; ++ni) {
      int gn = n0 + nq * 4 + ni;
      float pi = acc[ni][0] * aI[0] + acc[ni][1] * aI[1] +
                 acc[ni][2] * aI[2] + acc[ni][3] * aI[3];
      float pj = acc[ni][0] * aJ[0] + acc[ni][1] * aJ[1] +
                 acc[ni][2] * aJ[2] + acc[ni][3] * aJ[3];
      // jq and jq^1 cover the same head (j=4jq..4jq+3 => h=jq>>1)
      pi += __shfl_xor(pi, 1, 16);
      pj += __shfl_xor(pj, 1, 16);
      if (gn < N) {
        __half2 pk[2];
        pk[0] = __floats2half2_rn(acc[ni][0], acc[ni][1]);
        pk[1] = __floats2half2_rn(acc[ni][2], acc[ni][3]);
        *(uint2*)&xwh[(size_t)gn * 64 + jq * 4] = *(uint2*)pk;
        if (!(jq & 1)) {
          int h = jq >> 1;
          ai[gn * 8 + h] = pi;
          aj[gn * 8 + h] = pj;
        }
        pmax = fmaxf(pmax, pj);
      }
    }
  }
  #pragma unroll
  for (int off = 1; off < 64; off <<= 1)
    pmax = fmaxf(pmax, __shfl_xor(pmax, off, 64));
  __syncthreads();
  if ((tid & 63) == 0) red[tid >> 6] = pmax;
  __syncthreads();
  if (tid == 0) {
    float m = fmaxf(fmaxf(red[0], red[1]), fmaxf(red[2], red[3]));
    atomicMax(maxslot, f2ord(m));
  }
}

// Layer 3 projection: xw3(fp32) = x@W3 (64x4), H=4, C=1, + global aj max.
__global__ __launch_bounds__(256) void gemm_att4_kernel(
    const float* __restrict__ x, const float* __restrict__ W,
    const float* __restrict__ att, int N, float* __restrict__ xw3,
    float* __restrict__ ai, float* __restrict__ aj,
    unsigned* __restrict__ maxslot) {
  __shared__ float red[4];
  int t = blockIdx.x * 256 + threadIdx.x;
  int n = t >> 2;
  int j = t & 3;
  float pj = -FLT_MAX;
  if (n < N) {
    const float* xr = x + (size_t)n * 64;
    float acc = 0.f;
    #pragma unroll
    for (int k = 0; k < 64; ++k) acc += xr[k] * W[k * 4 + j];
    xw3[n * 4 + j] = acc;
    ai[n * 4 + j] = acc * att[j * 2];
    pj = acc * att[j * 2 + 1];
    aj[n * 4 + j] = pj;
  }
  float pmax = pj;
  #pragma unroll
  for (int off = 1; off < 64; off <<= 1)
    pmax = fmaxf(pmax, __shfl_xor(pmax, off, 64));
  if ((threadIdx.x & 63) == 0) red[threadIdx.x >> 6] = pmax;
  __syncthreads();
  if (threadIdx.x == 0) {
    float m = fmaxf(fmaxf(red[0], red[1]), fmaxf(red[2], red[3]));
    atomicMax(maxslot, f2ord(m));
  }
}

// Layers 1-2 aggregation: block = 4 nodes (1 wave each).
// Wave = 4 edge-slots x 16 lanes; lane holds 4 features f=4*li..4*li+3 as
// one 8B fp16x4 load. 4 edges in flight per slot. fp32 accumulate.
__global__ __launch_bounds__(256) void gather64_kernel(
    const __half* __restrict__ xwh, const float* __restrict__ ai,
    const float* __restrict__ aj, const int* __restrict__ rowstart,
    const int* __restrict__ col, const float* __restrict__ bias, int N,
    int relu, float* __restrict__ out, const unsigned* __restrict__ maxslot) {
  int n = blockIdx.x * 4 + (threadIdx.x >> 6);
  if (n >= N) return;
  float M = ord2f(*maxslot);
  int lane = threadIdx.x & 63;
  int slot = lane >> 4;   // which edge in the 4-group
  int li = lane & 15;     // feature quad
  int f4 = li * 4;
  int h = li >> 1;
  int r0 = rowstart[n], r1 = rowstart[n + 1];
  float ain = ai[n * 8 + h];
  float m = ain + M;               // >= local max (M >= all aj)
  m = (m > 0.f) ? m : 0.2f * m;    // leaky monotone => m >= local emax
  float dn = 0.f;
  float4 acc = make_float4(0.f, 0.f, 0.f, 0.f);
  int e = r0 + slot;
  for (; e + 12 < r1; e += 16) {   // 4 edges per slot in flight
    int sA = clampN(col[e],      N);
    int sB = clampN(col[e + 4],  N);
    int sC = clampN(col[e + 8],  N);
    int sD = clampN(col[e + 12], N);
    float aA = aj[sA * 8 + h], aB = aj[sB * 8 + h];
    float aC = aj[sC * 8 + h], aD = aj[sD * 8 + h];
    uint2 rA = *(const uint2*)&xwh[(size_t)sA * 64 + f4];
    uint2 rB = *(const uint2*)&xwh[(size_t)sB * 64 + f4];
    uint2 rC = *(const uint2*)&xwh[(size_t)sC * 64 + f4];
    uint2 rD = *(const uint2*)&xwh[(size_t)sD * 64 + f4];
    float eA = ain + aA; eA = (eA > 0.f) ? eA : 0.2f * eA;
    float eB = ain + aB; eB = (eB > 0.f) ? eB : 0.2f * eB;
    float eC = ain + aC; eC = (eC > 0.f) ? eC : 0.2f * eC;
    float eD = ain + aD; eD = (eD > 0.f) ? eD : 0.2f * eD;
    float pA = __expf(eA - m), pB = __expf(eB - m);
    float pC = __expf(eC - m), pD = __expf(eD - m);
    dn += (pA + pB) + (pC + pD);
    float2 A0 = __half22float2(*(__half2*)&rA.x), A1 = __half22float2(*(__half2*)&rA.y);
    float2 B0 = __half22float2(*(__half2*)&rB.x), B1 = __half22float2(*(__half2*)&rB.y);
    float2 C0 = __half22float2(*(__half2*)&rC.x), C1 = __half22float2(*(__half2*)&rC.y);
    float2 D0 = __half22float2(*(__half2*)&rD.x), D1 = __half22float2(*(__half2*)&rD.y);
    acc.x += pA * A0.x + pB * B0.x + pC * C0.x + pD * D0.x;
    acc.y += pA * A0.y + pB * B0.y + pC * C0.y + pD * D0.y;
    acc.z += pA * A1.x + pB * B1.x + pC * C1.x + pD * D1.x;
    acc.w += pA * A1.y + pB * B1.y + pC * C1.y + pD * D1.y;
  }
  for (; e < r1; e += 4) {
    int s = clampN(col[e], N);
    float a = aj[s * 8 + h];
    uint2 r = *(const uint2*)&xwh[(size_t)s * 64 + f4];
    float ev = ain + a; ev = (ev > 0.f) ? ev : 0.2f * ev;
    float p = __expf(ev - m);
    dn += p;
    float2 v0 = __half22float2(*(__half2*)&r.x);
    float2 v1 = __half22float2(*(__half2*)&r.y);
    acc.x += p * v0.x; acc.y += p * v0.y;
    acc.z += p * v1.x; acc.w += p * v1.y;
  }
  // reduce the 4 slots (lane bits 4 and 5)
  dn += __shfl_xor(dn, 16); dn += __shfl_xor(dn, 32);
  acc.x += __shfl_xor(acc.x, 16); acc.x += __shfl_xor(acc.x, 32);
  acc.y += __shfl_xor(acc.y, 16); acc.y += __shfl_xor(acc.y, 32);
  acc.z += __shfl_xor(acc.z, 16); acc.z += __shfl_xor(acc.z, 32);
  acc.w += __shfl_xor(acc.w, 16); acc.w += __shfl_xor(acc.w, 32);
  if (slot == 0) {
    float4 bv = *(const float4*)&bias[f4];
    float inv = 1.f / dn;
    float4 o = make_float4(acc.x * inv + bv.x, acc.y * inv + bv.y,
                           acc.z * inv + bv.z, acc.w * inv + bv.w);
    if (relu) {
      o.x = fmaxf(o.x, 0.f); o.y = fmaxf(o.y, 0.f);
      o.z = fmaxf(o.z, 0.f); o.w = fmaxf(o.w, 0.f);
    }
    *(float4*)&out[(size_t)n * 64 + f4] = o;
  }
}

// Layer 3 aggregation + head-mean + bias, single pass, unrolled x4 (fp32).
__global__ __launch_bounds__(256) void gather4_kernel(
    const float* __restrict__ xw3, const float* __restrict__ ai,
    const float* __restrict__ aj, const int* __restrict__ rowstart,
    const int* __restrict__ col, const float* __restrict__ b3, int N,
    float* __restrict__ out, const unsigned* __restrict__ maxslot) {
  int t = blockIdx.x * 256 + threadIdx.x;
  int n = t >> 2;
  if (n >= N) return;
  float M = ord2f(*maxslot);
  int h = t & 3;
  int r0 = rowstart[n], r1 = rowstart[n + 1];
  float ain = ai[n * 4 + h];
  float m = ain + M;
  m = (m > 0.f) ? m : 0.2f * m;
  float denom = 0.f, acc = 0.f;
  int e = r0;
  for (; e + 4 <= r1; e += 4) {
    int s0 = clampN(col[e + 0], N);
    int s1 = clampN(col[e + 1], N);
    int s2 = clampN(col[e + 2], N);
    int s3 = clampN(col[e + 3], N);
    float a0 = aj[s0 * 4 + h], a1 = aj[s1 * 4 + h];
    float a2 = aj[s2 * 4 + h], a3 = aj[s3 * 4 + h];
    float x0 = xw3[s0 * 4 + h], x1 = xw3[s1 * 4 + h];
    float x2 = xw3[s2 * 4 + h], x3 = xw3[s3 * 4 + h];
    float e0 = ain + a0; e0 = (e0 > 0.f) ? e0 : 0.2f * e0;
    float e1 = ain + a1; e1 = (e1 > 0.f) ? e1 : 0.2f * e1;
    float e2 = ain + a2; e2 = (e2 > 0.f) ? e2 : 0.2f * e2;
    float e3 = ain + a3; e3 = (e3 > 0.f) ? e3 : 0.2f * e3;
    float p0 = __expf(e0 - m), p1 = __expf(e1 - m);
    float p2 = __expf(e2 - m), p3 = __expf(e3 - m);
    denom += (p0 + p1) + (p2 + p3);
    acc += p0 * x0; acc += p1 * x1; acc += p2 * x2; acc += p3 * x3;
  }
  for (; e < r1; ++e) {
    int s = clampN(col[e], N);
    float ev = ain + aj[s * 4 + h];
    ev = (ev > 0.f) ? ev : 0.2f * ev;
    float p = __expf(ev - m);
    denom += p;
    acc += p * xw3[s * 4 + h];
  }
  float o = acc / denom;
  o += __shfl_xor(o, 1, 4);
  o += __shfl_xor(o, 2, 4);
  o *= 0.25f;
  if (h == 0) out[n] = o + b3[0];
}

extern "C" void kernel_launch(void* const* d_in, const int* in_sizes, int n_in,
                              void* d_out, int out_size, void* d_ws, size_t ws_size,
                              hipStream_t stream) {
  const float* X    = (const float*)d_in[0];
  const int*   ei   = (const int*)d_in[1];
  const float* W1   = (const float*)d_in[2];
  const float* att1 = (const float*)d_in[3];
  const float* b1   = (const float*)d_in[4];
  const float* W2   = (const float*)d_in[5];
  const float* att2 = (const float*)d_in[6];
  const float* b2   = (const float*)d_in[7];
  const float* W3   = (const float*)d_in[8];
  const float* att3 = (const float*)d_in[9];
  const float* b3   = (const float*)d_in[10];
  float* out = (float*)d_out;

  const int N  = in_sizes[0] / FDIM;   // 50000
  const int E  = in_sizes[1] / 2;      // 800000
  const int ET = E + N;
  const int NB = (N + BNODES - 1) >> BSHIFT;  // 391 buckets (<=512)

  char* ws = (char*)d_ws;
  auto carve = [&](size_t bytes) {
    char* p = ws; ws += (bytes + 15) & ~(size_t)15; return p;
  };
  __half*   xwh       = (__half*)carve((size_t)N * 64 * 2);  // fp16 rows
  float*    hfeat     = (float*)carve((size_t)N * 64 * 4);
  float*    xw3       = (float*)carve((size_t)N * 4 * 4);
  float*    ai        = (float*)carve((size_t)N * 8 * 4);
  float*    aj        = (float*)carve((size_t)N * 8 * 4);
  int*      rowstart  = (int*)carve((size_t)(N + 1) * 4);
  int*      colidx    = (int*)carve((size_t)ET * 4);
  int*      stflag    = (int*)carve(16);
  unsigned* maxslot   = (unsigned*)carve(16);
  int*      bucketCnt = (int*)carve(512 * 4);
  int*      bucketBas = (int*)carve(513 * 4);
  int*      bucketFil = (int*)carve(512 * 4);
  size_t need = (size_t)(ws - (char*)d_ws);
  if (ws_size < need) return;
  // pairbuf aliases xwh+xw3 region? keep it simple: alias hfeat (12.8MB >= ET*4=3.4MB);
  // CSR build completes before layer-1 gather writes hfeat.
  unsigned* pairbuf = (unsigned*)hfeat;

  // ---- CSR build: bucketed counting sort (once; shared by all 3 layers) ----
  init_kernel<<<(NB + 255) / 256 + 1, 256, 0, stream>>>(ei, E, bucketCnt, NB, maxslot, stflag);
  hist_kernel<<<128, 256, 0, stream>>>(ei, stflag, E, N, NB, bucketCnt);
  bucket_scan_kernel<<<1, 512, 0, stream>>>(bucketCnt, NB, bucketBas, bucketFil,
                                            rowstart, N, ET);
  binscatter_kernel<<<(ET + BINCH - 1) / BINCH, 256, 0, stream>>>(
      ei, stflag, E, N, NB, bucketFil, pairbuf, ET);
  bucketbuild_kernel<<<NB, 256, 0, stream>>>(pairbuf, bucketBas, N, ET,
                                             rowstart, colidx);

  const int nodeBlocks4 = (N + 3) / 4;
  const int laneBlocks4 = (N * 4 + 255) / 256;
  const int gemmTiles   = (N + 63) / 64;

  // ---- layer 1 ----
  gemm_att64_kernel<<<gemmTiles, 256, 0, stream>>>(X, W1, att1, N, xwh, ai, aj, maxslot + 0);
  gather64_kernel<<<nodeBlocks4, 256, 0, stream>>>(xwh, ai, aj, rowstart, colidx,
                                                   b1, N, 1, hfeat, maxslot + 0);
  // ---- layer 2 ----
  gemm_att64_kernel<<<gemmTiles, 256, 0, stream>>>(hfeat, W2, att2, N, xwh, ai, aj, maxslot + 1);
  gather64_kernel<<<nodeBlocks4, 256, 0, stream>>>(xwh, ai, aj, rowstart, colidx,
                                                   b2, N, 1, hfeat, maxslot + 1);
  // ---- layer 3 ----
  gemm_att4_kernel<<<laneBlocks4, 256, 0, stream>>>(hfeat, W3, att3, N, xw3, ai, aj, maxslot + 2);
  gather4_kernel<<<laneBlocks4, 256, 0, stream>>>(xw3, ai, aj, rowstart, colidx,
                                                  b3, N, out, maxslot + 2);
}

// Round 10
// 240.984 us; speedup vs baseline: 2.6652x; 1.0768x over previous
//
#include <hip/hip_runtime.h>
#include <hip/hip_bf16.h>
#include <hip/hip_fp16.h>
#include <float.h>

// GAT, 3 layers: (8,8,concat) -> relu -> (8,8,concat) -> relu -> (4,1,mean)
// N=50000, E=800000 (+N self-loops).
// R9 -> R10:
//  * Global-max softmax guard REMOVED: exp shift cancels exactly in the
//    ratio; glorot stats give |e|<~10 << 88 (fp32 overflow). Kills pmax
//    reductions, atomicMax, maxslot loads, and an ordering dependency.
//  * Layer-3 projection FUSED into layer-2 gather epilogue (all lanes hold
//    the full row post-reduce; 16 fma + 4 shfl steps). gemm_att4 dispatch
//    and the 12.8MB hfeat write are gone.
//  * (xw3, aj3) stored interleaved as float2 pairs -> gather4 does one 8B
//    random load per edge instead of two 4B ones.
// CSR build (bucketed counting sort) and fp16 xwh unchanged from R9.

#define FDIM 64
#define BSHIFT 7                 // 128 nodes per bucket
#define BNODES (1 << BSHIFT)
#define BINCH 8192               // edges per binscatter block

__device__ __forceinline__ int clampN(int v, int N) {
  return ((unsigned)v >= (unsigned)N) ? 0 : v;
}

// zero bucketCount; block 0 detects edge_index word stride
// (int64 upload => odd 32-bit words all zero since ids < 2^31).
__global__ __launch_bounds__(256) void init_kernel(
    const int* __restrict__ ei, int E, int* __restrict__ bucketCount, int NB,
    int* __restrict__ flag) {
  int i = blockIdx.x * 256 + threadIdx.x;
  if (i < NB) bucketCount[i] = 0;
  if (blockIdx.x == 0) {
    __shared__ int any;
    if (threadIdx.x == 0) any = 0;
    __syncthreads();
    int idx = 2 * threadIdx.x + 1;
    int v = (idx < 2 * E) ? ei[idx] : 0;
    if (v != 0) atomicOr(&any, 1);
    __syncthreads();
    if (threadIdx.x == 0) *flag = any ? 1 : 2;
  }
}

// coarse histogram of dst buckets (LDS-accumulated, few global atomics)
__global__ __launch_bounds__(256) void hist_kernel(
    const int* __restrict__ ei, const int* __restrict__ flag, int E, int N,
    int NB, int* __restrict__ bucketCount) {
  __shared__ int hist[512];
  int st = *flag;
  for (int i = threadIdx.x; i < NB; i += 256) hist[i] = 0;
  __syncthreads();
  int ET = E + N;
  for (int e = blockIdx.x * 256 + threadIdx.x; e < ET; e += gridDim.x * 256) {
    int dst = (e < E) ? clampN(ei[(size_t)st * (E + e)], N) : (e - E);
    atomicAdd(&hist[dst >> BSHIFT], 1);
  }
  __syncthreads();
  for (int i = threadIdx.x; i < NB; i += 256)
    if (hist[i]) atomicAdd(&bucketCount[i], hist[i]);
}

// 1-block scan of NB (<=512) bucket counts -> bucketBase (excl), fill=base
__global__ __launch_bounds__(512) void bucket_scan_kernel(
    const int* __restrict__ bucketCount, int NB, int* __restrict__ bucketBase,
    int* __restrict__ bucketFill, int* __restrict__ rowstart, int N, int ET) {
  __shared__ int s[512];
  int t = threadIdx.x;
  int v = (t < NB) ? bucketCount[t] : 0;
  s[t] = v;
  __syncthreads();
  for (int off = 1; off < 512; off <<= 1) {
    int x = (t >= off) ? s[t - off] : 0;
    __syncthreads();
    s[t] += x;
    __syncthreads();
  }
  if (t < NB) {
    int excl = s[t] - v;
    bucketBase[t] = excl;
    bucketFill[t] = excl;
  }
  if (t == 0) {
    bucketBase[NB] = s[511];  // == ET
    rowstart[N] = ET;
  }
}

// each block owns BINCH contiguous edges: LDS hist -> per-bucket global
// reservation -> write packed (src<<7|localdst) into per-bucket streams
__global__ __launch_bounds__(256) void binscatter_kernel(
    const int* __restrict__ ei, const int* __restrict__ flag, int E, int N,
    int NB, int* __restrict__ bucketFill, unsigned* __restrict__ pairbuf,
    int ET) {
  __shared__ int hist[512];
  __shared__ int cursor[512];
  int st = *flag;
  int e0 = blockIdx.x * BINCH;
  int e1 = min(e0 + BINCH, ET);
  for (int i = threadIdx.x; i < NB; i += 256) hist[i] = 0;
  __syncthreads();
  for (int e = e0 + threadIdx.x; e < e1; e += 256) {
    int dst = (e < E) ? clampN(ei[(size_t)st * (E + e)], N) : (e - E);
    atomicAdd(&hist[dst >> BSHIFT], 1);
  }
  __syncthreads();
  for (int i = threadIdx.x; i < NB; i += 256)
    cursor[i] = hist[i] ? atomicAdd(&bucketFill[i], hist[i]) : 0;
  __syncthreads();
  for (int e = e0 + threadIdx.x; e < e1; e += 256) {
    int src, dst;
    if (e < E) {
      src = clampN(ei[(size_t)st * e], N);
      dst = clampN(ei[(size_t)st * (E + e)], N);
    } else {
      src = e - E; dst = e - E;
    }
    int pos = atomicAdd(&cursor[dst >> BSHIFT], 1);
    if ((unsigned)pos < (unsigned)ET)
      pairbuf[pos] = ((unsigned)src << BSHIFT) | (unsigned)(dst & (BNODES - 1));
  }
}

// one block per bucket: local degree count -> LDS scan -> rowstart; then
// cursor-scatter col within the bucket's contiguous edge range (L2-local)
__global__ __launch_bounds__(256) void bucketbuild_kernel(
    const unsigned* __restrict__ pairbuf, const int* __restrict__ bucketBase,
    int N, int ET, int* __restrict__ rowstart, int* __restrict__ col) {
  __shared__ int s[BNODES];
  int b = blockIdx.x;
  int t = threadIdx.x;
  int base = bucketBase[b], end = bucketBase[b + 1];
  int n0 = b << BSHIFT;
  int nn = min(BNODES, N - n0);
  if (t < BNODES) s[t] = 0;
  __syncthreads();
  for (int e = base + t; e < end; e += 256) {
    int li = pairbuf[e] & (BNODES - 1);
    atomicAdd(&s[li], 1);
  }
  __syncthreads();
  int myd = (t < BNODES) ? s[t] : 0;
  for (int off = 1; off < BNODES; off <<= 1) {
    int v = (t >= off && t < BNODES) ? s[t - off] : 0;
    __syncthreads();
    if (t < BNODES) s[t] += v;
    __syncthreads();
  }
  int excl = (t < BNODES) ? (s[t] - myd) : 0;
  if (t < nn) rowstart[n0 + t] = base + excl;
  __syncthreads();
  if (t < BNODES) s[t] = excl;  // cursors
  __syncthreads();
  for (int e = base + t; e < end; e += 256) {
    unsigned p = pairbuf[e];
    int li = p & (BNODES - 1);
    int pos = base + atomicAdd(&s[li], 1);
    if ((unsigned)pos < (unsigned)ET) col[pos] = (int)(p >> BSHIFT);
  }
}

// Layers 1-2 projection: xwh(fp16) = x@W (64x64) + fp32 scores.
// Block = 256 threads; tile = 64 nodes; thread computes a 4x4 output block.
__global__ __launch_bounds__(256) void gemm_att64_kernel(
    const float* __restrict__ x, const float* __restrict__ W,
    const float* __restrict__ att, int N, __half* __restrict__ xwh,
    float* __restrict__ ai, float* __restrict__ aj) {
  __shared__ float Wl[64 * 64];
  __shared__ float xqT[64 * 68];  // [k][n], stride 68: 272B rows (16B aligned)
  int tid = threadIdx.x;
  for (int i = tid; i < 64 * 64; i += 256) Wl[i] = W[i];
  int jq = tid & 15, nq = tid >> 4;
  float aI[4], aJ[4];
  #pragma unroll
  for (int ji = 0; ji < 4; ++ji) {
    int j = jq * 4 + ji, h = j >> 3, c = j & 7;
    aI[ji] = att[h * 16 + c];
    aJ[ji] = att[h * 16 + 8 + c];
  }
  int ntiles = (N + 63) >> 6;
  for (int tile = blockIdx.x; tile < ntiles; tile += gridDim.x) {
    int n0 = tile << 6;
    __syncthreads();  // protect xqT reuse
    for (int idx = tid; idx < 4096; idx += 256) {
      int n = idx >> 6, k = idx & 63;   // per wave: k = lane (coalesced)
      int gn = n0 + n;
      xqT[k * 68 + n] = (gn < N) ? x[(size_t)gn * 64 + k] : 0.f;
    }
    __syncthreads();
    float acc[4][4];
    #pragma unroll
    for (int i = 0; i < 4; ++i)
      #pragma unroll
      for (int j = 0; j < 4; ++j) acc[i][j] = 0.f;
    #pragma unroll 8
    for (int k = 0; k < 64; ++k) {
      float4 xv = *(const float4*)&xqT[k * 68 + nq * 4];
      float4 wv = *(const float4*)&Wl[k * 64 + jq * 4];
      acc[0][0] += xv.x * wv.x; acc[0][1] += xv.x * wv.y;
      acc[0][2] += xv.x * wv.z; acc[0][3] += xv.x * wv.w;
      acc[1][0] += xv.y * wv.x; acc[1][1] += xv.y * wv.y;
      acc[1][2] += xv.y * wv.z; acc[1][3] += xv.y * wv.w;
      acc[2][0] += xv.z * wv.x; acc[2][1] += xv.z * wv.y;
      acc[2][2] += xv.z * wv.z; acc[2][3] += xv.z * wv.w;
      acc[3][0] += xv.w * wv.x; acc[3][1] += xv.w * wv.y;
      acc[3][2] += xv.w * wv.z; acc[3][3] += xv.w * wv.w;
    }
    #pragma unroll
    for (int ni = 0; ni < 4; ++ni) {
      int gn = n0 + nq * 4 + ni;
      float pi = acc[ni][0] * aI[0] + acc[ni][1] * aI[1] +
                 acc[ni][2] * aI[2] + acc[ni][3] * aI[3];
      float pj = acc[ni][0] * aJ[0] + acc[ni][1] * aJ[1] +
                 acc[ni][2] * aJ[2] + acc[ni][3] * aJ[3];
      // jq and jq^1 cover the same head (j=4jq..4jq+3 => h=jq>>1)
      pi += __shfl_xor(pi, 1, 16);
      pj += __shfl_xor(pj, 1, 16);
      if (gn < N) {
        __half2 pk[2];
        pk[0] = __floats2half2_rn(acc[ni][0], acc[ni][1]);
        pk[1] = __floats2half2_rn(acc[ni][2], acc[ni][3]);
        *(uint2*)&xwh[(size_t)gn * 64 + jq * 4] = *(uint2*)pk;
        if (!(jq & 1)) {
          int h = jq >> 1;
          ai[gn * 8 + h] = pi;
          aj[gn * 8 + h] = pj;
        }
      }
    }
  }
}

// Layers 1-2 aggregation: block = 4 nodes (1 wave each).
// Wave = 4 edge-slots x 16 lanes; lane holds 4 features as one 8B fp16x4 load.
// No max-shift: exp(e) directly (|e| <~ 10 << 88, shift cancels in ratio).
// fuse3: compute layer-3 projection from the finished row in-register and
// write pk3 (xw3,aj3 interleaved) + ai3 instead of the hfeat row.
__global__ __launch_bounds__(256) void gather64_kernel(
    const __half* __restrict__ xwh, const float* __restrict__ ai,
    const float* __restrict__ aj, const int* __restrict__ rowstart,
    const int* __restrict__ col, const float* __restrict__ bias, int N,
    float* __restrict__ out, int fuse3, const float* __restrict__ W3,
    const float* __restrict__ att3, float* __restrict__ pk3,
    float* __restrict__ ai3) {
  int n = blockIdx.x * 4 + (threadIdx.x >> 6);
  if (n >= N) return;
  int lane = threadIdx.x & 63;
  int slot = lane >> 4;   // which edge in the 4-group
  int li = lane & 15;     // feature quad
  int f4 = li * 4;
  int h = li >> 1;
  int r0 = rowstart[n], r1 = rowstart[n + 1];
  float ain = ai[n * 8 + h];
  float dn = 0.f;
  float4 acc = make_float4(0.f, 0.f, 0.f, 0.f);
  int e = r0 + slot;
  for (; e + 12 < r1; e += 16) {   // 4 edges per slot in flight
    int sA = clampN(col[e],      N);
    int sB = clampN(col[e + 4],  N);
    int sC = clampN(col[e + 8],  N);
    int sD = clampN(col[e + 12], N);
    float aA = aj[sA * 8 + h], aB = aj[sB * 8 + h];
    float aC = aj[sC * 8 + h], aD = aj[sD * 8 + h];
    uint2 rA = *(const uint2*)&xwh[(size_t)sA * 64 + f4];
    uint2 rB = *(const uint2*)&xwh[(size_t)sB * 64 + f4];
    uint2 rC = *(const uint2*)&xwh[(size_t)sC * 64 + f4];
    uint2 rD = *(const uint2*)&xwh[(size_t)sD * 64 + f4];
    float eA = ain + aA; eA = (eA > 0.f) ? eA : 0.2f * eA;
    float eB = ain + aB; eB = (eB > 0.f) ? eB : 0.2f * eB;
    float eC = ain + aC; eC = (eC > 0.f) ? eC : 0.2f * eC;
    float eD = ain + aD; eD = (eD > 0.f) ? eD : 0.2f * eD;
    float pA = __expf(eA), pB = __expf(eB);
    float pC = __expf(eC), pD = __expf(eD);
    dn += (pA + pB) + (pC + pD);
    float2 A0 = __half22float2(*(__half2*)&rA.x), A1 = __half22float2(*(__half2*)&rA.y);
    float2 B0 = __half22float2(*(__half2*)&rB.x), B1 = __half22float2(*(__half2*)&rB.y);
    float2 C0 = __half22float2(*(__half2*)&rC.x), C1 = __half22float2(*(__half2*)&rC.y);
    float2 D0 = __half22float2(*(__half2*)&rD.x), D1 = __half22float2(*(__half2*)&rD.y);
    acc.x += pA * A0.x + pB * B0.x + pC * C0.x + pD * D0.x;
    acc.y += pA * A0.y + pB * B0.y + pC * C0.y + pD * D0.y;
    acc.z += pA * A1.x + pB * B1.x + pC * C1.x + pD * D1.x;
    acc.w += pA * A1.y + pB * B1.y + pC * C1.y + pD * D1.y;
  }
  for (; e < r1; e += 4) {
    int s = clampN(col[e], N);
    float a = aj[s * 8 + h];
    uint2 r = *(const uint2*)&xwh[(size_t)s * 64 + f4];
    float ev = ain + a; ev = (ev > 0.f) ? ev : 0.2f * ev;
    float p = __expf(ev);
    dn += p;
    float2 v0 = __half22float2(*(__half2*)&r.x);
    float2 v1 = __half22float2(*(__half2*)&r.y);
    acc.x += p * v0.x; acc.y += p * v0.y;
    acc.z += p * v1.x; acc.w += p * v1.y;
  }
  // reduce the 4 slots (lane bits 4 and 5) -> all lanes hold full sums
  dn += __shfl_xor(dn, 16); dn += __shfl_xor(dn, 32);
  acc.x += __shfl_xor(acc.x, 16); acc.x += __shfl_xor(acc.x, 32);
  acc.y += __shfl_xor(acc.y, 16); acc.y += __shfl_xor(acc.y, 32);
  acc.z += __shfl_xor(acc.z, 16); acc.z += __shfl_xor(acc.z, 32);
  acc.w += __shfl_xor(acc.w, 16); acc.w += __shfl_xor(acc.w, 32);
  float4 bv = *(const float4*)&bias[f4];
  float inv = 1.f / dn;
  float4 o = make_float4(fmaxf(acc.x * inv + bv.x, 0.f),
                         fmaxf(acc.y * inv + bv.y, 0.f),
                         fmaxf(acc.z * inv + bv.z, 0.f),
                         fmaxf(acc.w * inv + bv.w, 0.f));  // relu fused
  if (!fuse3) {
    if (slot == 0) *(float4*)&out[(size_t)n * 64 + f4] = o;
    return;
  }
  // ---- fused layer-3 projection: pa[j] = sum_f row[f] * W3[f][j] ----
  // o is identical across slots (full reduce above); W3 rows are float4.
  float4 w0 = *(const float4*)&W3[(f4 + 0) * 4];
  float4 w1 = *(const float4*)&W3[(f4 + 1) * 4];
  float4 w2 = *(const float4*)&W3[(f4 + 2) * 4];
  float4 w3 = *(const float4*)&W3[(f4 + 3) * 4];
  float pa0 = o.x * w0.x + o.y * w1.x + o.z * w2.x + o.w * w3.x;
  float pa1 = o.x * w0.y + o.y * w1.y + o.z * w2.y + o.w * w3.y;
  float pa2 = o.x * w0.z + o.y * w1.z + o.z * w2.z + o.w * w3.z;
  float pa3 = o.x * w0.w + o.y * w1.w + o.z * w2.w + o.w * w3.w;
  #pragma unroll
  for (int off = 1; off < 16; off <<= 1) {
    pa0 += __shfl_xor(pa0, off, 16);
    pa1 += __shfl_xor(pa1, off, 16);
    pa2 += __shfl_xor(pa2, off, 16);
    pa3 += __shfl_xor(pa3, off, 16);
  }
  if (lane == 0) {
    // pk3[n][h] = (xw3_h, aj3_h) interleaved; ai3[n][h] separate
    float a0 = att3[0], a1 = att3[1], a2 = att3[2], a3 = att3[3];
    float a4 = att3[4], a5 = att3[5], a6 = att3[6], a7 = att3[7];
    *(float4*)&pk3[(size_t)n * 8 + 0] = make_float4(pa0, pa0 * a1, pa1, pa1 * a3);
    *(float4*)&pk3[(size_t)n * 8 + 4] = make_float4(pa2, pa2 * a5, pa3, pa3 * a7);
    *(float4*)&ai3[(size_t)n * 4] = make_float4(pa0 * a0, pa1 * a2, pa2 * a4, pa3 * a6);
  }
}

// Layer 3 aggregation + head-mean + bias. 4 lanes per node, one 8B
// (xw3,aj3) load per edge per lane. No max-shift.
__global__ __launch_bounds__(256) void gather4_kernel(
    const float* __restrict__ pk3, const float* __restrict__ ai3,
    const int* __restrict__ rowstart, const int* __restrict__ col,
    const float* __restrict__ b3, int N, float* __restrict__ out) {
  int t = blockIdx.x * 256 + threadIdx.x;
  int n = t >> 2;
  if (n >= N) return;
  int h = t & 3;
  int r0 = rowstart[n], r1 = rowstart[n + 1];
  float ain = ai3[n * 4 + h];
  float denom = 0.f, acc = 0.f;
  int e = r0;
  for (; e + 4 <= r1; e += 4) {
    int s0 = clampN(col[e + 0], N);
    int s1 = clampN(col[e + 1], N);
    int s2 = clampN(col[e + 2], N);
    int s3 = clampN(col[e + 3], N);
    float2 v0 = *(const float2*)&pk3[(size_t)s0 * 8 + h * 2];
    float2 v1 = *(const float2*)&pk3[(size_t)s1 * 8 + h * 2];
    float2 v2 = *(const float2*)&pk3[(size_t)s2 * 8 + h * 2];
    float2 v3 = *(const float2*)&pk3[(size_t)s3 * 8 + h * 2];
    float e0 = ain + v0.y; e0 = (e0 > 0.f) ? e0 : 0.2f * e0;
    float e1 = ain + v1.y; e1 = (e1 > 0.f) ? e1 : 0.2f * e1;
    float e2 = ain + v2.y; e2 = (e2 > 0.f) ? e2 : 0.2f * e2;
    float e3 = ain + v3.y; e3 = (e3 > 0.f) ? e3 : 0.2f * e3;
    float p0 = __expf(e0), p1 = __expf(e1);
    float p2 = __expf(e2), p3 = __expf(e3);
    denom += (p0 + p1) + (p2 + p3);
    acc += p0 * v0.x; acc += p1 * v1.x; acc += p2 * v2.x; acc += p3 * v3.x;
  }
  for (; e < r1; ++e) {
    int s = clampN(col[e], N);
    float2 v = *(const float2*)&pk3[(size_t)s * 8 + h * 2];
    float ev = ain + v.y;
    ev = (ev > 0.f) ? ev : 0.2f * ev;
    float p = __expf(ev);
    denom += p;
    acc += p * v.x;
  }
  float o = acc / denom;
  o += __shfl_xor(o, 1, 4);
  o += __shfl_xor(o, 2, 4);
  o *= 0.25f;
  if (h == 0) out[n] = o + b3[0];
}

extern "C" void kernel_launch(void* const* d_in, const int* in_sizes, int n_in,
                              void* d_out, int out_size, void* d_ws, size_t ws_size,
                              hipStream_t stream) {
  const float* X    = (const float*)d_in[0];
  const int*   ei   = (const int*)d_in[1];
  const float* W1   = (const float*)d_in[2];
  const float* att1 = (const float*)d_in[3];
  const float* b1   = (const float*)d_in[4];
  const float* W2   = (const float*)d_in[5];
  const float* att2 = (const float*)d_in[6];
  const float* b2   = (const float*)d_in[7];
  const float* W3   = (const float*)d_in[8];
  const float* att3 = (const float*)d_in[9];
  const float* b3   = (const float*)d_in[10];
  float* out = (float*)d_out;

  const int N  = in_sizes[0] / FDIM;   // 50000
  const int E  = in_sizes[1] / 2;      // 800000
  const int ET = E + N;
  const int NB = (N + BNODES - 1) >> BSHIFT;  // 391 buckets (<=512)

  char* ws = (char*)d_ws;
  auto carve = [&](size_t bytes) {
    char* p = ws; ws += (bytes + 15) & ~(size_t)15; return p;
  };
  __half*   xwh       = (__half*)carve((size_t)N * 64 * 2);  // fp16 rows
  float*    hfeat     = (float*)carve((size_t)N * 64 * 4);
  float*    pk3       = (float*)carve((size_t)N * 8 * 4);   // (xw3,aj3) pairs
  float*    ai3       = (float*)carve((size_t)N * 4 * 4);
  float*    ai        = (float*)carve((size_t)N * 8 * 4);
  float*    aj        = (float*)carve((size_t)N * 8 * 4);
  int*      rowstart  = (int*)carve((size_t)(N + 1) * 4);
  int*      colidx    = (int*)carve((size_t)ET * 4);
  int*      stflag    = (int*)carve(16);
  int*      bucketCnt = (int*)carve(512 * 4);
  int*      bucketBas = (int*)carve(513 * 4);
  int*      bucketFil = (int*)carve(512 * 4);
  size_t need = (size_t)(ws - (char*)d_ws);
  if (ws_size < need) return;
  // pairbuf aliases hfeat (12.8MB >= ET*4=3.4MB); CSR build completes before
  // layer-1 gather writes hfeat.
  unsigned* pairbuf = (unsigned*)hfeat;

  // ---- CSR build: bucketed counting sort (once; shared by all 3 layers) ----
  init_kernel<<<(NB + 255) / 256 + 1, 256, 0, stream>>>(ei, E, bucketCnt, NB, stflag);
  hist_kernel<<<128, 256, 0, stream>>>(ei, stflag, E, N, NB, bucketCnt);
  bucket_scan_kernel<<<1, 512, 0, stream>>>(bucketCnt, NB, bucketBas, bucketFil,
                                            rowstart, N, ET);
  binscatter_kernel<<<(ET + BINCH - 1) / BINCH, 256, 0, stream>>>(
      ei, stflag, E, N, NB, bucketFil, pairbuf, ET);
  bucketbuild_kernel<<<NB, 256, 0, stream>>>(pairbuf, bucketBas, N, ET,
                                             rowstart, colidx);

  const int nodeBlocks4 = (N + 3) / 4;
  const int laneBlocks4 = (N * 4 + 255) / 256;
  const int gemmTiles   = (N + 63) / 64;

  // ---- layer 1 ----
  gemm_att64_kernel<<<gemmTiles, 256, 0, stream>>>(X, W1, att1, N, xwh, ai, aj);
  gather64_kernel<<<nodeBlocks4, 256, 0, stream>>>(
      xwh, ai, aj, rowstart, colidx, b1, N, hfeat, 0, nullptr, nullptr,
      nullptr, nullptr);
  // ---- layer 2 (+ fused layer-3 projection) ----
  gemm_att64_kernel<<<gemmTiles, 256, 0, stream>>>(hfeat, W2, att2, N, xwh, ai, aj);
  gather64_kernel<<<nodeBlocks4, 256, 0, stream>>>(
      xwh, ai, aj, rowstart, colidx, b2, N, nullptr, 1, W3, att3, pk3, ai3);
  // ---- layer 3 aggregation ----
  gather4_kernel<<<laneBlocks4, 256, 0, stream>>>(pk3, ai3, rowstart, colidx,
                                                  b3, N, out);
}